// Round 4
// baseline (722.525 us; speedup 1.0000x reference)
//
#include <hip/hip_runtime.h>
#include <math.h>

#define NN 50000
#define NE 600000
#define HID 128
#define NH 4
#define HD 32
#define NRBF 40
#define SCALE 0.17677669529663687f  // 1/sqrt(32)

// ---------------------------------------------------------------------------
// Generic out[M,128] = A[M,128] @ W[128,128] + bias.  fp32, register-tiled.
// A tile staged in LDS transposed with XOR swizzle (sw = k & 124) so the
// main-loop ds_read_b128 (16 lanes at 16B stride) is bank-conflict-free.
// W rows streamed from global (64KB -> L1/L2 resident, broadcast across lanes).
// ---------------------------------------------------------------------------
__global__ __launch_bounds__(256) void k_gemm128(const float* __restrict__ A,
                                                 const float* __restrict__ W,
                                                 const float* __restrict__ bias,
                                                 float* __restrict__ out, int M) {
  __shared__ float xs[128 * 128];  // (k, n) at xs[k*128 + (n ^ (k & 124))]
  int tid = threadIdx.x;
  int row0 = blockIdx.x * 128;

  // stage A tile: coalesced float4 loads, transposed scalar stores (4-way max)
#pragma unroll
  for (int rep = 0; rep < 16; ++rep) {
    int idx = rep * 256 + tid;
    int c4 = (idx & 31) * 4;  // k base of this quad
    int n = idx >> 5;         // node within tile
    int gn = row0 + n;
    float4 a = make_float4(0.f, 0.f, 0.f, 0.f);
    if (gn < M) a = *(const float4*)&A[gn * 128 + c4];
    int sw = c4;  // == (k & 124) for k in [c4, c4+3]
    xs[(c4 + 0) * 128 + (n ^ sw)] = a.x;
    xs[(c4 + 1) * 128 + (n ^ sw)] = a.y;
    xs[(c4 + 2) * 128 + (n ^ sw)] = a.z;
    xs[(c4 + 3) * 128 + (n ^ sw)] = a.w;
  }
  __syncthreads();

  int tn = tid & 15, tc = tid >> 4;
  int nA = 4 * tn, nB = 64 + 4 * tn, c0 = 8 * tc;
  float acc[8][8];
#pragma unroll
  for (int i = 0; i < 8; ++i)
#pragma unroll
    for (int j = 0; j < 8; ++j) acc[i][j] = 0.f;

#pragma unroll 4
  for (int k = 0; k < 128; ++k) {
    int sw = k & 124;
    float4 xa = *(const float4*)&xs[k * 128 + (nA ^ sw)];
    float4 xb = *(const float4*)&xs[k * 128 + (nB ^ sw)];
    float4 wa = *(const float4*)&W[k * 128 + c0];
    float4 wb = *(const float4*)&W[k * 128 + c0 + 4];
    float xv[8] = {xa.x, xa.y, xa.z, xa.w, xb.x, xb.y, xb.z, xb.w};
    float wv[8] = {wa.x, wa.y, wa.z, wa.w, wb.x, wb.y, wb.z, wb.w};
#pragma unroll
    for (int i = 0; i < 8; ++i)
#pragma unroll
      for (int j = 0; j < 8; ++j) acc[i][j] = fmaf(xv[i], wv[j], acc[i][j]);
  }

  float4 b0 = *(const float4*)&bias[c0];
  float4 b1 = *(const float4*)&bias[c0 + 4];
  float bb[8] = {b0.x, b0.y, b0.z, b0.w, b1.x, b1.y, b1.z, b1.w};
#pragma unroll
  for (int i = 0; i < 8; ++i) {
    int n = (i < 4) ? (nA + i) : (nB + i - 4);
    int gn = row0 + n;
    if (gn < M) {
      float4 o0 = make_float4(acc[i][0] + bb[0], acc[i][1] + bb[1],
                              acc[i][2] + bb[2], acc[i][3] + bb[3]);
      float4 o1 = make_float4(acc[i][4] + bb[4], acc[i][5] + bb[5],
                              acc[i][6] + bb[6], acc[i][7] + bb[7]);
      *(float4*)&out[gn * 128 + c0] = o0;
      *(float4*)&out[gn * 128 + c0 + 4] = o1;
    }
  }
}

// ---------------------------------------------------------------------------
// geo bias: score[e][h] = silu(rbf[e]@Wg1 + bg1) @ Wg2 + bg2   (per 128-edge tile)
// Same GEMM structure (K=40), fused silu + [128,4] projection + cross-thread
// LDS reduction (stride 36 pad -> conflict-free scatter).
// ---------------------------------------------------------------------------
__global__ __launch_bounds__(256) void k_geo(const float* __restrict__ rbf,
                                             const float* __restrict__ Wg1,
                                             const float* __restrict__ bg1,
                                             const float* __restrict__ Wg2,
                                             const float* __restrict__ bg2,
                                             float* __restrict__ score) {
  __shared__ float rt[40 * 128];   // (k,e) at rt[k*128 + (e ^ (k & 124))]
  __shared__ float red[256 * 36];  // per-thread partials, padded stride
  int tid = threadIdx.x;
  int e0 = blockIdx.x * 128;

  // stage rbf tile: 128 edges x 40 floats = 1280 float4
#pragma unroll
  for (int rep = 0; rep < 5; ++rep) {
    int idx = rep * 256 + tid;
    int u = idx % 10;
    int e = idx / 10;
    int ge = e0 + e;
    float4 a = make_float4(0.f, 0.f, 0.f, 0.f);
    if (ge < NE) a = *(const float4*)&rbf[ge * NRBF + u * 4];
    int c4 = u * 4;
    rt[(c4 + 0) * 128 + (e ^ c4)] = a.x;
    rt[(c4 + 1) * 128 + (e ^ c4)] = a.y;
    rt[(c4 + 2) * 128 + (e ^ c4)] = a.z;
    rt[(c4 + 3) * 128 + (e ^ c4)] = a.w;
  }
  __syncthreads();

  int tn = tid & 15, tc = tid >> 4;
  int eA = 4 * tn, eB = 64 + 4 * tn, c0 = 8 * tc;
  float acc[8][8];
#pragma unroll
  for (int i = 0; i < 8; ++i)
#pragma unroll
    for (int j = 0; j < 8; ++j) acc[i][j] = 0.f;

#pragma unroll 4
  for (int k = 0; k < 40; ++k) {
    int sw = k & 124;
    float4 xa = *(const float4*)&rt[k * 128 + (eA ^ sw)];
    float4 xb = *(const float4*)&rt[k * 128 + (eB ^ sw)];
    float4 wa = *(const float4*)&Wg1[k * 128 + c0];
    float4 wb = *(const float4*)&Wg1[k * 128 + c0 + 4];
    float xv[8] = {xa.x, xa.y, xa.z, xa.w, xb.x, xb.y, xb.z, xb.w};
    float wv[8] = {wa.x, wa.y, wa.z, wa.w, wb.x, wb.y, wb.z, wb.w};
#pragma unroll
    for (int i = 0; i < 8; ++i)
#pragma unroll
      for (int j = 0; j < 8; ++j) acc[i][j] = fmaf(xv[i], wv[j], acc[i][j]);
  }

  // silu + project to 4 heads (per-thread partial over its 8 hidden cols)
  float4 g0 = *(const float4*)&bg1[c0];
  float4 g1 = *(const float4*)&bg1[c0 + 4];
  float bb[8] = {g0.x, g0.y, g0.z, g0.w, g1.x, g1.y, g1.z, g1.w};
  float4 w2r[8];
#pragma unroll
  for (int j = 0; j < 8; ++j) w2r[j] = *(const float4*)&Wg2[(c0 + j) * 4];
  float p[8][4];
#pragma unroll
  for (int i = 0; i < 8; ++i) {
    p[i][0] = p[i][1] = p[i][2] = p[i][3] = 0.f;
#pragma unroll
    for (int j = 0; j < 8; ++j) {
      float h = acc[i][j] + bb[j];
      float s = h / (1.f + __expf(-h));
      p[i][0] = fmaf(s, w2r[j].x, p[i][0]);
      p[i][1] = fmaf(s, w2r[j].y, p[i][1]);
      p[i][2] = fmaf(s, w2r[j].z, p[i][2]);
      p[i][3] = fmaf(s, w2r[j].w, p[i][3]);
    }
  }
#pragma unroll
  for (int i = 0; i < 8; ++i)
    *(float4*)&red[tid * 36 + i * 4] = make_float4(p[i][0], p[i][1], p[i][2], p[i][3]);
  __syncthreads();

  // reduce over the 16 hidden-block threads; 2 outputs per thread
#pragma unroll
  for (int r = 0; r < 2; ++r) {
    int oid = tid * 2 + r;
    int e = oid >> 2, hh = oid & 3;
    int tns, is;
    if (e < 64) { tns = e >> 2; is = e & 3; }
    else        { tns = (e - 64) >> 2; is = 4 + ((e - 64) & 3); }
    float sum = 0.f;
#pragma unroll
    for (int tcp = 0; tcp < 16; ++tcp)
      sum += red[(tcp * 16 + tns) * 36 + is * 4 + hh];
    int ge = e0 + e;
    if (ge < NE) score[ge * 4 + hh] = sum + bg2[hh];
  }
}

// ---------------------------------------------------------------------------
// per-(edge,head) score: Q[src].K[dst]/sqrt(Hd) + geo (already in score) +
// defect bias; also dst-degree histogram.
// ---------------------------------------------------------------------------
__global__ __launch_bounds__(256) void k_edge(const int* __restrict__ srcv,
                                              const int* __restrict__ dstv,
                                              const float* __restrict__ Q,
                                              const float* __restrict__ K,
                                              const int* __restrict__ isd,
                                              const float* __restrict__ db,
                                              float* __restrict__ score,
                                              int* __restrict__ cnt) {
  int gid = blockIdx.x * 256 + threadIdx.x;
  int e = gid >> 2, h = gid & 3;
  if (e >= NE) return;
  int s = srcv[e], d = dstv[e];
  const float4* q4 = (const float4*)&Q[s * HID + h * HD];
  const float4* k4 = (const float4*)&K[d * HID + h * HD];
  float dot = 0.f;
#pragma unroll
  for (int i = 0; i < 8; ++i) {
    float4 a = q4[i], b = k4[i];
    dot += a.x * b.x + a.y * b.y + a.z * b.z + a.w * b.w;
  }
  int code = isd[s] * 2 + isd[d];
  score[e * 4 + h] = fmaf(dot, SCALE, score[e * 4 + h] + db[h * 4 + code]);
  if (h == 0) atomicAdd(&cnt[d], 1);
}

// --------------------------- CSR build (3-kernel scan) ----------------------
__global__ void k_scan1(const int* __restrict__ cnt, int* __restrict__ bsum) {
  __shared__ int sd[256];
  int t = threadIdx.x;
  int i = blockIdx.x * 256 + t;
  sd[t] = (i < NN) ? cnt[i] : 0;
  __syncthreads();
  for (int off = 128; off > 0; off >>= 1) {
    if (t < off) sd[t] += sd[t + off];
    __syncthreads();
  }
  if (t == 0) bsum[blockIdx.x] = sd[0];
}

__global__ void k_scan2(const int* __restrict__ bsum, int* __restrict__ bpre,
                        int* __restrict__ offsets, int nb) {
  __shared__ int sd[256];
  int t = threadIdx.x;
  int v = (t < nb) ? bsum[t] : 0;
  sd[t] = v;
  __syncthreads();
  for (int off = 1; off < 256; off <<= 1) {
    int x = (t >= off) ? sd[t - off] : 0;
    __syncthreads();
    sd[t] += x;
    __syncthreads();
  }
  if (t < nb) bpre[t] = sd[t] - v;
  if (t == 255) offsets[NN] = sd[255];
}

__global__ void k_scan3(const int* __restrict__ cnt, const int* __restrict__ bpre,
                        int* __restrict__ offsets, int* __restrict__ cursor) {
  __shared__ int sd[256];
  int t = threadIdx.x;
  int i = blockIdx.x * 256 + t;
  int v = (i < NN) ? cnt[i] : 0;
  sd[t] = v;
  __syncthreads();
  for (int off = 1; off < 256; off <<= 1) {
    int x = (t >= off) ? sd[t - off] : 0;
    __syncthreads();
    sd[t] += x;
    __syncthreads();
  }
  int excl = sd[t] - v + bpre[blockIdx.x];
  if (i < NN) { offsets[i] = excl; cursor[i] = excl; }
}

__global__ void k_scatter(const int* __restrict__ dstv, int* __restrict__ cursor,
                          int* __restrict__ eids) {
  int e = blockIdx.x * 256 + threadIdx.x;
  if (e < NE) {
    int d = dstv[e];
    int pos = atomicAdd(&cursor[d], 1);
    eids[pos] = e;
  }
}

// ---------------------------------------------------------------------------
// per-dst segment softmax + weighted V aggregation. One 128-thread block per
// node; thread t = (head t>>5, dim t&31). No atomics: CSR edge list.
// ---------------------------------------------------------------------------
__global__ __launch_bounds__(128) void k_aggregate(const int* __restrict__ srcv,
                                                   const int* __restrict__ offsets,
                                                   const int* __restrict__ eids,
                                                   const float* __restrict__ score,
                                                   const float* __restrict__ V,
                                                   float* __restrict__ accum) {
  int b = blockIdx.x;
  int t = threadIdx.x;
  int h = t >> 5;
  int beg = offsets[b], end = offsets[b + 1];
  float m = -3.0e38f;
  for (int i = beg; i < end; ++i) {
    int e = eids[i];
    m = fmaxf(m, score[e * 4 + h]);
  }
  float den = 0.f, acc = 0.f;
  for (int i = beg; i < end; ++i) {
    int e = eids[i];
    float w = __expf(score[e * 4 + h] - m);
    den += w;
    acc = fmaf(w, V[srcv[e] * HID + t], acc);
  }
  accum[b * HID + t] = (end > beg) ? (acc / den) : 0.f;
}

// ---------------------------------------------------------------------------
extern "C" void kernel_launch(void* const* d_in, const int* in_sizes, int n_in,
                              void* d_out, int out_size, void* d_ws, size_t ws_size,
                              hipStream_t stream) {
  const float* x = (const float*)d_in[0];
  const int* ei = (const int*)d_in[1];
  const float* rbf = (const float*)d_in[2];
  const int* isd = (const int*)d_in[3];
  const float* Wq = (const float*)d_in[4];
  const float* bq = (const float*)d_in[5];
  const float* Wk = (const float*)d_in[6];
  const float* bk = (const float*)d_in[7];
  const float* Wv = (const float*)d_in[8];
  const float* bv = (const float*)d_in[9];
  const float* Wo = (const float*)d_in[10];
  const float* bo = (const float*)d_in[11];
  const float* Wg1 = (const float*)d_in[12];
  const float* bg1 = (const float*)d_in[13];
  const float* Wg2 = (const float*)d_in[14];
  const float* bg2 = (const float*)d_in[15];
  const float* db = (const float*)d_in[16];
  const int* srcv = ei;
  const int* dstv = ei + NE;

  char* p = (char*)d_ws;
  auto alloc = [&](size_t bytes) {
    void* r = (void*)p;
    p += (bytes + 255) & ~(size_t)255;
    return r;
  };
  float* Q = (float*)alloc((size_t)NN * HID * 4);
  float* Kb = (float*)alloc((size_t)NN * HID * 4);
  float* Vb = (float*)alloc((size_t)NN * HID * 4);
  float* score = (float*)alloc((size_t)NE * NH * 4);
  float* accum = (float*)alloc((size_t)NN * HID * 4);
  int* cnt = (int*)alloc((size_t)NN * 4);
  int* offsets = (int*)alloc((size_t)(NN + 1) * 4);
  int* cursor = (int*)alloc((size_t)NN * 4);
  int* eids = (int*)alloc((size_t)NE * 4);
  int* bsum = (int*)alloc(256 * 4);
  int* bpre = (int*)alloc(256 * 4);

  hipMemsetAsync(cnt, 0, (size_t)NN * 4, stream);

  int gQ = (NN + 127) / 128;       // 391
  int gE = (NE + 127) / 128;       // 4688
  int gES = (NE * NH + 255) / 256; // 9375
  int gS = (NN + 255) / 256;       // 196

  k_gemm128<<<gQ, 256, 0, stream>>>(x, Wq, bq, Q, NN);
  k_gemm128<<<gQ, 256, 0, stream>>>(x, Wk, bk, Kb, NN);
  k_gemm128<<<gQ, 256, 0, stream>>>(x, Wv, bv, Vb, NN);
  k_geo<<<gE, 256, 0, stream>>>(rbf, Wg1, bg1, Wg2, bg2, score);
  k_edge<<<gES, 256, 0, stream>>>(srcv, dstv, Q, Kb, isd, db, score, cnt);
  k_scan1<<<gS, 256, 0, stream>>>(cnt, bsum);
  k_scan2<<<1, 256, 0, stream>>>(bsum, bpre, offsets, gS);
  k_scan3<<<gS, 256, 0, stream>>>(cnt, bpre, offsets, cursor);
  k_scatter<<<(NE + 255) / 256, 256, 0, stream>>>(dstv, cursor, eids);
  k_aggregate<<<NN, 128, 0, stream>>>(srcv, offsets, eids, score, Vb, accum);
  k_gemm128<<<gQ, 256, 0, stream>>>(accum, Wo, bo, (float*)d_out, NN);
}

// Round 6
// 604.069 us; speedup vs baseline: 1.1961x; 1.1961x over previous
//
#include <hip/hip_runtime.h>
#include <math.h>

#define NN 50000
#define NE 600000
#define HID 128
#define NH 4
#define HD 32
#define NRBF 40
#define SCALE 0.17677669529663687f  // 1/sqrt(32)

typedef __attribute__((ext_vector_type(8))) __bf16 bf16x8;
typedef __attribute__((ext_vector_type(4))) __bf16 bf16x4;
typedef __attribute__((ext_vector_type(4))) float f32x4;

#define MFMA16(a, b, c) __builtin_amdgcn_mfma_f32_16x16x32_bf16(a, b, c, 0, 0, 0)

__device__ __forceinline__ void split2(float v, __bf16& h, __bf16& l) {
  h = (__bf16)v;          // RNE round to bf16
  l = (__bf16)(v - (float)h);  // residual, also bf16: total ~2^-17 rel err
}

// ---------------------------------------------------------------------------
// Weight prep: convert W[K x 128] fp32 (row-major, k-major) into MFMA B-frag
// ordered hi/lo bf16 buffers. Slot = ((nt*NKS + ks)*4 + kg)*16 + n holds the
// 8 bf16 for lane (kg*16+n) of tile (nt, ks): elements W[ks*32+kg*8+j][nt*16+n],
// zero-padded for k >= KREAL.
// ---------------------------------------------------------------------------
__global__ void k_prepw(const float* __restrict__ W, __bf16* __restrict__ hi,
                        __bf16* __restrict__ lo, int NKS, int KREAL) {
  int slot = blockIdx.x * 256 + threadIdx.x;
  int total = 8 * NKS * 4 * 16;
  if (slot >= total) return;
  int n = slot & 15, kg = (slot >> 4) & 3;
  int tt = slot >> 6;
  int ks = tt % NKS, nt = tt / NKS;
  bf16x8 h8, l8;
#pragma unroll
  for (int j = 0; j < 8; ++j) {
    int k = ks * 32 + kg * 8 + j;
    float v = (k < KREAL) ? W[k * 128 + nt * 16 + n] : 0.f;
    __bf16 h, l;
    split2(v, h, l);
    h8[j] = h;
    l8[j] = l;
  }
  *(bf16x8*)&hi[slot * 8] = h8;
  *(bf16x8*)&lo[slot * 8] = l8;
}

// ---------------------------------------------------------------------------
// Fused QKV: out{Q,K,V}[M,128] = x[M,128] @ W{q,k,v} + b.  Split-bf16 MFMA.
// x tile staged once as hi/lo fragment-ordered LDS; 4 waves split the 8
// n-tiles (2 each); 3 weight streams loop over preloaded B-frag registers.
// ---------------------------------------------------------------------------
__global__ __launch_bounds__(256) void k_qkv3(
    const float* __restrict__ x,
    const __bf16* __restrict__ qhi, const __bf16* __restrict__ qlo,
    const __bf16* __restrict__ khi, const __bf16* __restrict__ klo,
    const __bf16* __restrict__ vhi, const __bf16* __restrict__ vlo,
    const float* __restrict__ bq, const float* __restrict__ bk,
    const float* __restrict__ bv,
    float* __restrict__ Q, float* __restrict__ K, float* __restrict__ V,
    int M) {
  __shared__ __bf16 Ahi[16384];  // slot(mt,ks,kg,m)*8 ; 32KB
  __shared__ __bf16 Alo[16384];
  int t = threadIdx.x;
  int row0 = blockIdx.x * 128;

  // stage x tile: 128 rows x 32 float4, convert to hi/lo frags
#pragma unroll
  for (int rep = 0; rep < 16; ++rep) {
    int idx = rep * 256 + t;
    int e = idx >> 5, c = idx & 31;
    int gn = row0 + e;
    float4 a = (gn < M) ? *(const float4*)&x[gn * 128 + c * 4]
                        : make_float4(0.f, 0.f, 0.f, 0.f);
    int mt = e >> 4, m = e & 15, ks = c >> 3, kg = (c >> 1) & 3, half = c & 1;
    int base = ((((mt * 4 + ks) * 4 + kg) * 16) + m) * 8 + half * 4;
    bf16x4 h4, l4;
    __bf16 h, l;
    split2(a.x, h, l); h4[0] = h; l4[0] = l;
    split2(a.y, h, l); h4[1] = h; l4[1] = l;
    split2(a.z, h, l); h4[2] = h; l4[2] = l;
    split2(a.w, h, l); h4[3] = h; l4[3] = l;
    *(bf16x4*)&Ahi[base] = h4;
    *(bf16x4*)&Alo[base] = l4;
  }
  __syncthreads();

  int wave = t >> 6, l = t & 63;
  int lq = l >> 4, ln = l & 15;
  int nt0 = wave * 2;
  const __bf16* whi[3] = {qhi, khi, vhi};
  const __bf16* wlo[3] = {qlo, klo, vlo};
  const float* bias[3] = {bq, bk, bv};
  float* out[3] = {Q, K, V};
  const f32x4 fz = {0.f, 0.f, 0.f, 0.f};

#pragma unroll
  for (int w = 0; w < 3; ++w) {
    bf16x8 Bh[2][4], Bl[2][4];
#pragma unroll
    for (int ntl = 0; ntl < 2; ++ntl)
#pragma unroll
      for (int ks = 0; ks < 4; ++ks) {
        int bidx = (((nt0 + ntl) * 4 + ks) * 4 + lq) * 16 + ln;
        Bh[ntl][ks] = *(const bf16x8*)&whi[w][bidx * 8];
        Bl[ntl][ks] = *(const bf16x8*)&wlo[w][bidx * 8];
      }
    f32x4 acc[8][2];
#pragma unroll
    for (int mt = 0; mt < 8; ++mt) { acc[mt][0] = fz; acc[mt][1] = fz; }
#pragma unroll
    for (int mt = 0; mt < 8; ++mt)
#pragma unroll
      for (int ks = 0; ks < 4; ++ks) {
        int as = ((((mt * 4 + ks) * 4 + lq) * 16) + ln) * 8;
        bf16x8 ah = *(bf16x8*)&Ahi[as];
        bf16x8 al = *(bf16x8*)&Alo[as];
#pragma unroll
        for (int ntl = 0; ntl < 2; ++ntl) {
          acc[mt][ntl] = MFMA16(ah, Bh[ntl][ks], acc[mt][ntl]);
          acc[mt][ntl] = MFMA16(al, Bh[ntl][ks], acc[mt][ntl]);
          acc[mt][ntl] = MFMA16(ah, Bl[ntl][ks], acc[mt][ntl]);
        }
      }
    int n0 = nt0 * 16 + ln;
    float b0 = bias[w][n0], b1 = bias[w][n0 + 16];
#pragma unroll
    for (int mt = 0; mt < 8; ++mt)
#pragma unroll
      for (int reg = 0; reg < 4; ++reg) {
        int e = row0 + mt * 16 + lq * 4 + reg;
        if (e < M) {
          out[w][e * 128 + n0] = acc[mt][0][reg] + b0;
          out[w][e * 128 + n0 + 16] = acc[mt][1][reg] + b1;
        }
      }
  }
}

// ---------------------------------------------------------------------------
// Single-weight GEMM (output projection): out[M,128] = A @ W + b, split-bf16.
// ---------------------------------------------------------------------------
__global__ __launch_bounds__(256) void k_mm128(
    const float* __restrict__ A, const __bf16* __restrict__ whi,
    const __bf16* __restrict__ wlo, const float* __restrict__ bias,
    float* __restrict__ out, int M) {
  __shared__ __bf16 Ahi[16384];
  __shared__ __bf16 Alo[16384];
  int t = threadIdx.x;
  int row0 = blockIdx.x * 128;
#pragma unroll
  for (int rep = 0; rep < 16; ++rep) {
    int idx = rep * 256 + t;
    int e = idx >> 5, c = idx & 31;
    int gn = row0 + e;
    float4 a = (gn < M) ? *(const float4*)&A[gn * 128 + c * 4]
                        : make_float4(0.f, 0.f, 0.f, 0.f);
    int mt = e >> 4, m = e & 15, ks = c >> 3, kg = (c >> 1) & 3, half = c & 1;
    int base = ((((mt * 4 + ks) * 4 + kg) * 16) + m) * 8 + half * 4;
    bf16x4 h4, l4;
    __bf16 h, l;
    split2(a.x, h, l); h4[0] = h; l4[0] = l;
    split2(a.y, h, l); h4[1] = h; l4[1] = l;
    split2(a.z, h, l); h4[2] = h; l4[2] = l;
    split2(a.w, h, l); h4[3] = h; l4[3] = l;
    *(bf16x4*)&Ahi[base] = h4;
    *(bf16x4*)&Alo[base] = l4;
  }
  __syncthreads();

  int wave = t >> 6, l = t & 63;
  int lq = l >> 4, ln = l & 15;
  int nt0 = wave * 2;
  const f32x4 fz = {0.f, 0.f, 0.f, 0.f};
  bf16x8 Bh[2][4], Bl[2][4];
#pragma unroll
  for (int ntl = 0; ntl < 2; ++ntl)
#pragma unroll
    for (int ks = 0; ks < 4; ++ks) {
      int bidx = (((nt0 + ntl) * 4 + ks) * 4 + lq) * 16 + ln;
      Bh[ntl][ks] = *(const bf16x8*)&whi[bidx * 8];
      Bl[ntl][ks] = *(const bf16x8*)&wlo[bidx * 8];
    }
  f32x4 acc[8][2];
#pragma unroll
  for (int mt = 0; mt < 8; ++mt) { acc[mt][0] = fz; acc[mt][1] = fz; }
#pragma unroll
  for (int mt = 0; mt < 8; ++mt)
#pragma unroll
    for (int ks = 0; ks < 4; ++ks) {
      int as = ((((mt * 4 + ks) * 4 + lq) * 16) + ln) * 8;
      bf16x8 ah = *(bf16x8*)&Ahi[as];
      bf16x8 al = *(bf16x8*)&Alo[as];
#pragma unroll
      for (int ntl = 0; ntl < 2; ++ntl) {
        acc[mt][ntl] = MFMA16(ah, Bh[ntl][ks], acc[mt][ntl]);
        acc[mt][ntl] = MFMA16(al, Bh[ntl][ks], acc[mt][ntl]);
        acc[mt][ntl] = MFMA16(ah, Bl[ntl][ks], acc[mt][ntl]);
      }
    }
  int n0 = nt0 * 16 + ln;
  float b0 = bias[n0], b1 = bias[n0 + 16];
#pragma unroll
  for (int mt = 0; mt < 8; ++mt)
#pragma unroll
    for (int reg = 0; reg < 4; ++reg) {
      int e = row0 + mt * 16 + lq * 4 + reg;
      if (e < M) {
        out[e * 128 + n0] = acc[mt][0][reg] + b0;
        out[e * 128 + n0 + 16] = acc[mt][1][reg] + b1;
      }
    }
}

// ---------------------------------------------------------------------------
// geo bias via MFMA: score[e][h] = silu(rbf[e]@Wg1 + bg1) @ Wg2 + bg2.
// K=40 zero-padded to 64 (2 k-steps). Waves split edges (2 m-tiles each);
// epilogue does fp32 silu + per-lane partial projection + 16-lane butterfly.
// ---------------------------------------------------------------------------
__global__ __launch_bounds__(256) void k_geo_mfma(
    const float* __restrict__ rbf, const __bf16* __restrict__ g1hi,
    const __bf16* __restrict__ g1lo, const float* __restrict__ bg1,
    const float* __restrict__ Wg2, const float* __restrict__ bg2,
    float* __restrict__ score) {
  __shared__ __bf16 Ahi[8192];  // slot(mt,ks,kg,m)*8 ; 16KB
  __shared__ __bf16 Alo[8192];
  int t = threadIdx.x;
  int e0 = blockIdx.x * 128;

  // zero all slots (covers the K-pad region), then stage real data
  bf16x8 zz = {};
#pragma unroll
  for (int z = 0; z < 4; ++z) {
    *(bf16x8*)&Ahi[(z * 256 + t) * 8] = zz;
    *(bf16x8*)&Alo[(z * 256 + t) * 8] = zz;
  }
  __syncthreads();
#pragma unroll
  for (int rep = 0; rep < 5; ++rep) {
    int idx = rep * 256 + t;
    int e = idx / 10, c = idx % 10;
    int ge = e0 + e;
    float4 a = (ge < NE) ? *(const float4*)&rbf[ge * NRBF + c * 4]
                         : make_float4(0.f, 0.f, 0.f, 0.f);
    int k4 = c * 4;
    int mt = e >> 4, m = e & 15, ks = k4 >> 5, kg = (k4 >> 3) & 3,
        half = (k4 >> 2) & 1;
    int base = ((((mt * 2 + ks) * 4 + kg) * 16) + m) * 8 + half * 4;
    bf16x4 h4, l4;
    __bf16 h, l;
    split2(a.x, h, l); h4[0] = h; l4[0] = l;
    split2(a.y, h, l); h4[1] = h; l4[1] = l;
    split2(a.z, h, l); h4[2] = h; l4[2] = l;
    split2(a.w, h, l); h4[3] = h; l4[3] = l;
    *(bf16x4*)&Ahi[base] = h4;
    *(bf16x4*)&Alo[base] = l4;
  }
  __syncthreads();

  int wave = t >> 6, l = t & 63;
  int lq = l >> 4, ln = l & 15;
  int mtb = wave * 2;
  const f32x4 fz = {0.f, 0.f, 0.f, 0.f};
  f32x4 acc[2][8];
#pragma unroll
  for (int mtl = 0; mtl < 2; ++mtl)
#pragma unroll
    for (int nt = 0; nt < 8; ++nt) acc[mtl][nt] = fz;

#pragma unroll
  for (int ks = 0; ks < 2; ++ks) {
    bf16x8 ah[2], al[2];
#pragma unroll
    for (int mtl = 0; mtl < 2; ++mtl) {
      int as = (((((mtb + mtl) * 2 + ks) * 4 + lq) * 16) + ln) * 8;
      ah[mtl] = *(bf16x8*)&Ahi[as];
      al[mtl] = *(bf16x8*)&Alo[as];
    }
#pragma unroll
    for (int nt = 0; nt < 8; ++nt) {
      int bidx = ((nt * 2 + ks) * 4 + lq) * 16 + ln;
      bf16x8 bh = *(const bf16x8*)&g1hi[bidx * 8];
      bf16x8 bl = *(const bf16x8*)&g1lo[bidx * 8];
#pragma unroll
      for (int mtl = 0; mtl < 2; ++mtl) {
        acc[mtl][nt] = MFMA16(ah[mtl], bh, acc[mtl][nt]);
        acc[mtl][nt] = MFMA16(al[mtl], bh, acc[mtl][nt]);
        acc[mtl][nt] = MFMA16(ah[mtl], bl, acc[mtl][nt]);
      }
    }
  }

  // epilogue: silu + project to 4 heads; lane ln holds hidden col n=nt*16+ln
  float p[2][4][4];
#pragma unroll
  for (int mtl = 0; mtl < 2; ++mtl)
#pragma unroll
    for (int reg = 0; reg < 4; ++reg)
#pragma unroll
      for (int hh = 0; hh < 4; ++hh) p[mtl][reg][hh] = 0.f;
#pragma unroll
  for (int nt = 0; nt < 8; ++nt) {
    int n = nt * 16 + ln;
    float b1v = bg1[n];
    float4 w2 = *(const float4*)&Wg2[n * 4];
#pragma unroll
    for (int mtl = 0; mtl < 2; ++mtl)
#pragma unroll
      for (int reg = 0; reg < 4; ++reg) {
        float h = acc[mtl][nt][reg] + b1v;
        float s = h / (1.f + __expf(-h));
        p[mtl][reg][0] = fmaf(s, w2.x, p[mtl][reg][0]);
        p[mtl][reg][1] = fmaf(s, w2.y, p[mtl][reg][1]);
        p[mtl][reg][2] = fmaf(s, w2.z, p[mtl][reg][2]);
        p[mtl][reg][3] = fmaf(s, w2.w, p[mtl][reg][3]);
      }
  }
  // reduce over the 16 hidden lanes (butterfly)
#pragma unroll
  for (int off = 1; off < 16; off <<= 1)
#pragma unroll
    for (int mtl = 0; mtl < 2; ++mtl)
#pragma unroll
      for (int reg = 0; reg < 4; ++reg)
#pragma unroll
        for (int hh = 0; hh < 4; ++hh)
          p[mtl][reg][hh] += __shfl_xor(p[mtl][reg][hh], off, 64);
  // lane ln writes outputs o with o&15==ln: (reg=ln>>2, hh=ln&3), both mtl.
  // select value with static indices (avoid runtime-indexed array -> scratch)
#pragma unroll
  for (int mtl = 0; mtl < 2; ++mtl) {
    float v = 0.f;
#pragma unroll
    for (int reg = 0; reg < 4; ++reg)
#pragma unroll
      for (int hh = 0; hh < 4; ++hh)
        if (ln == reg * 4 + hh) v = p[mtl][reg][hh];
    int reg = ln >> 2, hh = ln & 3;
    int e = e0 + (mtb + mtl) * 16 + lq * 4 + reg;
    if (e < NE) score[e * 4 + hh] = v + bg2[hh];
  }
}

// ---------------------------------------------------------------------------
// per-(edge,head) score: Q[src].K[dst]/sqrt(Hd) + geo (already in score) +
// defect bias; also dst-degree histogram.
// ---------------------------------------------------------------------------
__global__ __launch_bounds__(256) void k_edge(const int* __restrict__ srcv,
                                              const int* __restrict__ dstv,
                                              const float* __restrict__ Q,
                                              const float* __restrict__ K,
                                              const int* __restrict__ isd,
                                              const float* __restrict__ db,
                                              float* __restrict__ score,
                                              int* __restrict__ cnt) {
  int gid = blockIdx.x * 256 + threadIdx.x;
  int e = gid >> 2, h = gid & 3;
  if (e >= NE) return;
  int s = srcv[e], d = dstv[e];
  const float4* q4 = (const float4*)&Q[s * HID + h * HD];
  const float4* k4 = (const float4*)&K[d * HID + h * HD];
  float dot = 0.f;
#pragma unroll
  for (int i = 0; i < 8; ++i) {
    float4 a = q4[i], b = k4[i];
    dot += a.x * b.x + a.y * b.y + a.z * b.z + a.w * b.w;
  }
  int code = isd[s] * 2 + isd[d];
  score[e * 4 + h] = fmaf(dot, SCALE, score[e * 4 + h] + db[h * 4 + code]);
  if (h == 0) atomicAdd(&cnt[d], 1);
}

// --------------------------- CSR build (3-kernel scan) ----------------------
__global__ void k_scan1(const int* __restrict__ cnt, int* __restrict__ bsum) {
  __shared__ int sd[256];
  int t = threadIdx.x;
  int i = blockIdx.x * 256 + t;
  sd[t] = (i < NN) ? cnt[i] : 0;
  __syncthreads();
  for (int off = 128; off > 0; off >>= 1) {
    if (t < off) sd[t] += sd[t + off];
    __syncthreads();
  }
  if (t == 0) bsum[blockIdx.x] = sd[0];
}

__global__ void k_scan2(const int* __restrict__ bsum, int* __restrict__ bpre,
                        int* __restrict__ offsets, int nb) {
  __shared__ int sd[256];
  int t = threadIdx.x;
  int v = (t < nb) ? bsum[t] : 0;
  sd[t] = v;
  __syncthreads();
  for (int off = 1; off < 256; off <<= 1) {
    int x = (t >= off) ? sd[t - off] : 0;
    __syncthreads();
    sd[t] += x;
    __syncthreads();
  }
  if (t < nb) bpre[t] = sd[t] - v;
  if (t == 255) offsets[NN] = sd[255];
}

__global__ void k_scan3(const int* __restrict__ cnt, const int* __restrict__ bpre,
                        int* __restrict__ offsets, int* __restrict__ cursor) {
  __shared__ int sd[256];
  int t = threadIdx.x;
  int i = blockIdx.x * 256 + t;
  int v = (i < NN) ? cnt[i] : 0;
  sd[t] = v;
  __syncthreads();
  for (int off = 1; off < 256; off <<= 1) {
    int x = (t >= off) ? sd[t - off] : 0;
    __syncthreads();
    sd[t] += x;
    __syncthreads();
  }
  int excl = sd[t] - v + bpre[blockIdx.x];
  if (i < NN) { offsets[i] = excl; cursor[i] = excl; }
}

__global__ void k_scatter(const int* __restrict__ dstv, int* __restrict__ cursor,
                          int* __restrict__ eids) {
  int e = blockIdx.x * 256 + threadIdx.x;
  if (e < NE) {
    int d = dstv[e];
    int pos = atomicAdd(&cursor[d], 1);
    eids[pos] = e;
  }
}

// ---------------------------------------------------------------------------
// per-dst segment softmax + weighted V aggregation (CSR, no atomics).
// ---------------------------------------------------------------------------
__global__ __launch_bounds__(128) void k_aggregate(const int* __restrict__ srcv,
                                                   const int* __restrict__ offsets,
                                                   const int* __restrict__ eids,
                                                   const float* __restrict__ score,
                                                   const float* __restrict__ V,
                                                   float* __restrict__ accum) {
  int b = blockIdx.x;
  int t = threadIdx.x;
  int h = t >> 5;
  int beg = offsets[b], end = offsets[b + 1];
  float m = -3.0e38f;
  for (int i = beg; i < end; ++i) {
    int e = eids[i];
    m = fmaxf(m, score[e * 4 + h]);
  }
  float den = 0.f, acc = 0.f;
  for (int i = beg; i < end; ++i) {
    int e = eids[i];
    float w = __expf(score[e * 4 + h] - m);
    den += w;
    acc = fmaf(w, V[srcv[e] * HID + t], acc);
  }
  accum[b * HID + t] = (end > beg) ? (acc / den) : 0.f;
}

// ---------------------------------------------------------------------------
extern "C" void kernel_launch(void* const* d_in, const int* in_sizes, int n_in,
                              void* d_out, int out_size, void* d_ws, size_t ws_size,
                              hipStream_t stream) {
  const float* x = (const float*)d_in[0];
  const int* ei = (const int*)d_in[1];
  const float* rbf = (const float*)d_in[2];
  const int* isd = (const int*)d_in[3];
  const float* Wq = (const float*)d_in[4];
  const float* bq = (const float*)d_in[5];
  const float* Wk = (const float*)d_in[6];
  const float* bk = (const float*)d_in[7];
  const float* Wv = (const float*)d_in[8];
  const float* bv = (const float*)d_in[9];
  const float* Wo = (const float*)d_in[10];
  const float* bo = (const float*)d_in[11];
  const float* Wg1 = (const float*)d_in[12];
  const float* bg1 = (const float*)d_in[13];
  const float* Wg2 = (const float*)d_in[14];
  const float* bg2 = (const float*)d_in[15];
  const float* db = (const float*)d_in[16];
  const int* srcv = ei;
  const int* dstv = ei + NE;

  char* p = (char*)d_ws;
  auto alloc = [&](size_t bytes) {
    void* r = (void*)p;
    p += (bytes + 255) & ~(size_t)255;
    return r;
  };
  float* Q = (float*)alloc((size_t)NN * HID * 4);
  float* Kb = (float*)alloc((size_t)NN * HID * 4);
  float* Vb = (float*)alloc((size_t)NN * HID * 4);
  float* score = (float*)alloc((size_t)NE * NH * 4);
  float* accum = (float*)alloc((size_t)NN * HID * 4);
  int* cnt = (int*)alloc((size_t)NN * 4);
  int* offsets = (int*)alloc((size_t)(NN + 1) * 4);
  int* cursor = (int*)alloc((size_t)NN * 4);
  int* eids = (int*)alloc((size_t)NE * 4);
  int* bsum = (int*)alloc(256 * 4);
  int* bpre = (int*)alloc(256 * 4);
  // split-bf16 weight frag buffers (2048 slots x 8 elems x 2B = 32KB each)
  __bf16* qhi = (__bf16*)alloc(2048 * 8 * 2);
  __bf16* qlo = (__bf16*)alloc(2048 * 8 * 2);
  __bf16* khi = (__bf16*)alloc(2048 * 8 * 2);
  __bf16* klo = (__bf16*)alloc(2048 * 8 * 2);
  __bf16* vhi = (__bf16*)alloc(2048 * 8 * 2);
  __bf16* vlo = (__bf16*)alloc(2048 * 8 * 2);
  __bf16* ohi = (__bf16*)alloc(2048 * 8 * 2);
  __bf16* olo = (__bf16*)alloc(2048 * 8 * 2);
  __bf16* g1hi = (__bf16*)alloc(1024 * 8 * 2);
  __bf16* g1lo = (__bf16*)alloc(1024 * 8 * 2);

  hipMemsetAsync(cnt, 0, (size_t)NN * 4, stream);

  int gQ = (NN + 127) / 128;       // 391
  int gE = (NE + 127) / 128;       // 4688
  int gES = (NE * NH + 255) / 256; // 9375
  int gS = (NN + 255) / 256;       // 196

  k_prepw<<<8, 256, 0, stream>>>(Wq, qhi, qlo, 4, 128);
  k_prepw<<<8, 256, 0, stream>>>(Wk, khi, klo, 4, 128);
  k_prepw<<<8, 256, 0, stream>>>(Wv, vhi, vlo, 4, 128);
  k_prepw<<<8, 256, 0, stream>>>(Wo, ohi, olo, 4, 128);
  k_prepw<<<4, 256, 0, stream>>>(Wg1, g1hi, g1lo, 2, NRBF);

  k_qkv3<<<gQ, 256, 0, stream>>>(x, qhi, qlo, khi, klo, vhi, vlo,
                                 bq, bk, bv, Q, Kb, Vb, NN);
  k_geo_mfma<<<gE, 256, 0, stream>>>(rbf, g1hi, g1lo, bg1, Wg2, bg2, score);
  k_edge<<<gES, 256, 0, stream>>>(srcv, dstv, Q, Kb, isd, db, score, cnt);
  k_scan1<<<gS, 256, 0, stream>>>(cnt, bsum);
  k_scan2<<<1, 256, 0, stream>>>(bsum, bpre, offsets, gS);
  k_scan3<<<gS, 256, 0, stream>>>(cnt, bpre, offsets, cursor);
  k_scatter<<<(NE + 255) / 256, 256, 0, stream>>>(dstv, cursor, eids);
  k_aggregate<<<NN, 128, 0, stream>>>(srcv, offsets, eids, score, Vb, accum);
  k_mm128<<<gQ, 256, 0, stream>>>(accum, ohi, olo, bo, (float*)d_out, NN);
}

// Round 10
// 496.977 us; speedup vs baseline: 1.4538x; 1.2155x over previous
//
#include <hip/hip_runtime.h>
#include <math.h>

#define NN 50000
#define NE 600000
#define HID 128
#define NH 4
#define HD 32
#define NRBF 40
#define SCALE 0.17677669529663687f  // 1/sqrt(32)

typedef __attribute__((ext_vector_type(8))) __bf16 bf16x8;
typedef __attribute__((ext_vector_type(4))) __bf16 bf16x4;
typedef __attribute__((ext_vector_type(4))) float f32x4;

#define MFMA16(a, b, c) __builtin_amdgcn_mfma_f32_16x16x32_bf16(a, b, c, 0, 0, 0)

__device__ __forceinline__ void split2(float v, __bf16& h, __bf16& l) {
  h = (__bf16)v;          // RNE round to bf16
  l = (__bf16)(v - (float)h);  // residual, also bf16: total ~2^-17 rel err
}

// ---------------------------------------------------------------------------
// Weight prep: convert W[K x 128] fp32 (row-major, k-major) into MFMA B-frag
// ordered hi/lo bf16 buffers. Slot = ((nt*NKS + ks)*4 + kg)*16 + n holds the
// 8 bf16 for lane (kg*16+n) of tile (nt, ks): elements W[ks*32+kg*8+j][nt*16+n],
// zero-padded for k >= KREAL.
// ---------------------------------------------------------------------------
__global__ void k_prepw(const float* __restrict__ W, __bf16* __restrict__ hi,
                        __bf16* __restrict__ lo, int NKS, int KREAL) {
  int slot = blockIdx.x * 256 + threadIdx.x;
  int total = 8 * NKS * 4 * 16;
  if (slot >= total) return;
  int n = slot & 15, kg = (slot >> 4) & 3;
  int tt = slot >> 6;
  int ks = tt % NKS, nt = tt / NKS;
  bf16x8 h8, l8;
#pragma unroll
  for (int j = 0; j < 8; ++j) {
    int k = ks * 32 + kg * 8 + j;
    float v = (k < KREAL) ? W[k * 128 + nt * 16 + n] : 0.f;
    __bf16 h, l;
    split2(v, h, l);
    h8[j] = h;
    l8[j] = l;
  }
  *(bf16x8*)&hi[slot * 8] = h8;
  *(bf16x8*)&lo[slot * 8] = l8;
}

// ---------------------------------------------------------------------------
// Fused QKV: out{Q,K,V}[M,128] = x[M,128] @ W{q,k,v} + b.  Split-bf16 MFMA.
// ---------------------------------------------------------------------------
__global__ __launch_bounds__(256) void k_qkv3(
    const float* __restrict__ x,
    const __bf16* __restrict__ qhi, const __bf16* __restrict__ qlo,
    const __bf16* __restrict__ khi, const __bf16* __restrict__ klo,
    const __bf16* __restrict__ vhi, const __bf16* __restrict__ vlo,
    const float* __restrict__ bq, const float* __restrict__ bk,
    const float* __restrict__ bv,
    float* __restrict__ Q, float* __restrict__ K, float* __restrict__ V,
    int M) {
  __shared__ __bf16 Ahi[16384];  // slot(mt,ks,kg,m)*8 ; 32KB
  __shared__ __bf16 Alo[16384];
  int t = threadIdx.x;
  int row0 = blockIdx.x * 128;

#pragma unroll
  for (int rep = 0; rep < 16; ++rep) {
    int idx = rep * 256 + t;
    int e = idx >> 5, c = idx & 31;
    int gn = row0 + e;
    float4 a = (gn < M) ? *(const float4*)&x[gn * 128 + c * 4]
                        : make_float4(0.f, 0.f, 0.f, 0.f);
    int mt = e >> 4, m = e & 15, ks = c >> 3, kg = (c >> 1) & 3, half = c & 1;
    int base = ((((mt * 4 + ks) * 4 + kg) * 16) + m) * 8 + half * 4;
    bf16x4 h4, l4;
    __bf16 h, l;
    split2(a.x, h, l); h4[0] = h; l4[0] = l;
    split2(a.y, h, l); h4[1] = h; l4[1] = l;
    split2(a.z, h, l); h4[2] = h; l4[2] = l;
    split2(a.w, h, l); h4[3] = h; l4[3] = l;
    *(bf16x4*)&Ahi[base] = h4;
    *(bf16x4*)&Alo[base] = l4;
  }
  __syncthreads();

  int wave = t >> 6, l = t & 63;
  int lq = l >> 4, ln = l & 15;
  int nt0 = wave * 2;
  const __bf16* whi[3] = {qhi, khi, vhi};
  const __bf16* wlo[3] = {qlo, klo, vlo};
  const float* bias[3] = {bq, bk, bv};
  float* out[3] = {Q, K, V};
  const f32x4 fz = {0.f, 0.f, 0.f, 0.f};

#pragma unroll
  for (int w = 0; w < 3; ++w) {
    bf16x8 Bh[2][4], Bl[2][4];
#pragma unroll
    for (int ntl = 0; ntl < 2; ++ntl)
#pragma unroll
      for (int ks = 0; ks < 4; ++ks) {
        int bidx = (((nt0 + ntl) * 4 + ks) * 4 + lq) * 16 + ln;
        Bh[ntl][ks] = *(const bf16x8*)&whi[w][bidx * 8];
        Bl[ntl][ks] = *(const bf16x8*)&wlo[w][bidx * 8];
      }
    f32x4 acc[8][2];
#pragma unroll
    for (int mt = 0; mt < 8; ++mt) { acc[mt][0] = fz; acc[mt][1] = fz; }
#pragma unroll
    for (int mt = 0; mt < 8; ++mt)
#pragma unroll
      for (int ks = 0; ks < 4; ++ks) {
        int as = ((((mt * 4 + ks) * 4 + lq) * 16) + ln) * 8;
        bf16x8 ah = *(bf16x8*)&Ahi[as];
        bf16x8 al = *(bf16x8*)&Alo[as];
#pragma unroll
        for (int ntl = 0; ntl < 2; ++ntl) {
          acc[mt][ntl] = MFMA16(ah, Bh[ntl][ks], acc[mt][ntl]);
          acc[mt][ntl] = MFMA16(al, Bh[ntl][ks], acc[mt][ntl]);
          acc[mt][ntl] = MFMA16(ah, Bl[ntl][ks], acc[mt][ntl]);
        }
      }
    int n0 = nt0 * 16 + ln;
    float b0 = bias[w][n0], b1 = bias[w][n0 + 16];
#pragma unroll
    for (int mt = 0; mt < 8; ++mt)
#pragma unroll
      for (int reg = 0; reg < 4; ++reg) {
        int e = row0 + mt * 16 + lq * 4 + reg;
        if (e < M) {
          out[w][e * 128 + n0] = acc[mt][0][reg] + b0;
          out[w][e * 128 + n0 + 16] = acc[mt][1][reg] + b1;
        }
      }
  }
}

// ---------------------------------------------------------------------------
// Single-weight GEMM (output projection): out[M,128] = A @ W + b, split-bf16.
// ---------------------------------------------------------------------------
__global__ __launch_bounds__(256) void k_mm128(
    const float* __restrict__ A, const __bf16* __restrict__ whi,
    const __bf16* __restrict__ wlo, const float* __restrict__ bias,
    float* __restrict__ out, int M) {
  __shared__ __bf16 Ahi[16384];
  __shared__ __bf16 Alo[16384];
  int t = threadIdx.x;
  int row0 = blockIdx.x * 128;
#pragma unroll
  for (int rep = 0; rep < 16; ++rep) {
    int idx = rep * 256 + t;
    int e = idx >> 5, c = idx & 31;
    int gn = row0 + e;
    float4 a = (gn < M) ? *(const float4*)&A[gn * 128 + c * 4]
                        : make_float4(0.f, 0.f, 0.f, 0.f);
    int mt = e >> 4, m = e & 15, ks = c >> 3, kg = (c >> 1) & 3, half = c & 1;
    int base = ((((mt * 4 + ks) * 4 + kg) * 16) + m) * 8 + half * 4;
    bf16x4 h4, l4;
    __bf16 h, l;
    split2(a.x, h, l); h4[0] = h; l4[0] = l;
    split2(a.y, h, l); h4[1] = h; l4[1] = l;
    split2(a.z, h, l); h4[2] = h; l4[2] = l;
    split2(a.w, h, l); h4[3] = h; l4[3] = l;
    *(bf16x4*)&Ahi[base] = h4;
    *(bf16x4*)&Alo[base] = l4;
  }
  __syncthreads();

  int wave = t >> 6, l = t & 63;
  int lq = l >> 4, ln = l & 15;
  int nt0 = wave * 2;
  const f32x4 fz = {0.f, 0.f, 0.f, 0.f};
  bf16x8 Bh[2][4], Bl[2][4];
#pragma unroll
  for (int ntl = 0; ntl < 2; ++ntl)
#pragma unroll
    for (int ks = 0; ks < 4; ++ks) {
      int bidx = (((nt0 + ntl) * 4 + ks) * 4 + lq) * 16 + ln;
      Bh[ntl][ks] = *(const bf16x8*)&whi[bidx * 8];
      Bl[ntl][ks] = *(const bf16x8*)&wlo[bidx * 8];
    }
  f32x4 acc[8][2];
#pragma unroll
  for (int mt = 0; mt < 8; ++mt) { acc[mt][0] = fz; acc[mt][1] = fz; }
#pragma unroll
  for (int mt = 0; mt < 8; ++mt)
#pragma unroll
    for (int ks = 0; ks < 4; ++ks) {
      int as = ((((mt * 4 + ks) * 4 + lq) * 16) + ln) * 8;
      bf16x8 ah = *(bf16x8*)&Ahi[as];
      bf16x8 al = *(bf16x8*)&Alo[as];
#pragma unroll
      for (int ntl = 0; ntl < 2; ++ntl) {
        acc[mt][ntl] = MFMA16(ah, Bh[ntl][ks], acc[mt][ntl]);
        acc[mt][ntl] = MFMA16(al, Bh[ntl][ks], acc[mt][ntl]);
        acc[mt][ntl] = MFMA16(ah, Bl[ntl][ks], acc[mt][ntl]);
      }
    }
  int n0 = nt0 * 16 + ln;
  float b0 = bias[n0], b1 = bias[n0 + 16];
#pragma unroll
  for (int mt = 0; mt < 8; ++mt)
#pragma unroll
    for (int reg = 0; reg < 4; ++reg) {
      int e = row0 + mt * 16 + lq * 4 + reg;
      if (e < M) {
        out[e * 128 + n0] = acc[mt][0][reg] + b0;
        out[e * 128 + n0 + 16] = acc[mt][1][reg] + b1;
      }
    }
}

// ---------------------------------------------------------------------------
// geo+defect bias via MFMA: biasE[e][h] = silu(rbf[e]@Wg1+bg1)@Wg2 + bg2
//                                        + defect_bias[h][code(e)]
// K=40 zero-padded to 64. Epilogue folds the defect lookup (srcv/dstv/isd
// gathers are latency-hidden across 4688 independent blocks).
// ---------------------------------------------------------------------------
__global__ __launch_bounds__(256) void k_geo_mfma(
    const float* __restrict__ rbf, const __bf16* __restrict__ g1hi,
    const __bf16* __restrict__ g1lo, const float* __restrict__ bg1,
    const float* __restrict__ Wg2, const float* __restrict__ bg2,
    const int* __restrict__ srcv, const int* __restrict__ dstv,
    const int* __restrict__ isd, const float* __restrict__ db,
    float* __restrict__ biasE) {
  __shared__ __bf16 Ahi[8192];  // slot(mt,ks,kg,m)*8 ; 16KB
  __shared__ __bf16 Alo[8192];
  int t = threadIdx.x;
  int e0 = blockIdx.x * 128;

  bf16x8 zz = {};
#pragma unroll
  for (int z = 0; z < 4; ++z) {
    *(bf16x8*)&Ahi[(z * 256 + t) * 8] = zz;
    *(bf16x8*)&Alo[(z * 256 + t) * 8] = zz;
  }
  __syncthreads();
#pragma unroll
  for (int rep = 0; rep < 5; ++rep) {
    int idx = rep * 256 + t;
    int e = idx / 10, c = idx % 10;
    int ge = e0 + e;
    float4 a = (ge < NE) ? *(const float4*)&rbf[ge * NRBF + c * 4]
                         : make_float4(0.f, 0.f, 0.f, 0.f);
    int k4 = c * 4;
    int mt = e >> 4, m = e & 15, ks = k4 >> 5, kg = (k4 >> 3) & 3,
        half = (k4 >> 2) & 1;
    int base = ((((mt * 2 + ks) * 4 + kg) * 16) + m) * 8 + half * 4;
    bf16x4 h4, l4;
    __bf16 h, l;
    split2(a.x, h, l); h4[0] = h; l4[0] = l;
    split2(a.y, h, l); h4[1] = h; l4[1] = l;
    split2(a.z, h, l); h4[2] = h; l4[2] = l;
    split2(a.w, h, l); h4[3] = h; l4[3] = l;
    *(bf16x4*)&Ahi[base] = h4;
    *(bf16x4*)&Alo[base] = l4;
  }
  __syncthreads();

  int wave = t >> 6, l = t & 63;
  int lq = l >> 4, ln = l & 15;
  int mtb = wave * 2;
  const f32x4 fz = {0.f, 0.f, 0.f, 0.f};
  f32x4 acc[2][8];
#pragma unroll
  for (int mtl = 0; mtl < 2; ++mtl)
#pragma unroll
    for (int nt = 0; nt < 8; ++nt) acc[mtl][nt] = fz;

#pragma unroll
  for (int ks = 0; ks < 2; ++ks) {
    bf16x8 ah[2], al[2];
#pragma unroll
    for (int mtl = 0; mtl < 2; ++mtl) {
      int as = (((((mtb + mtl) * 2 + ks) * 4 + lq) * 16) + ln) * 8;
      ah[mtl] = *(bf16x8*)&Ahi[as];
      al[mtl] = *(bf16x8*)&Alo[as];
    }
#pragma unroll
    for (int nt = 0; nt < 8; ++nt) {
      int bidx = ((nt * 2 + ks) * 4 + lq) * 16 + ln;
      bf16x8 bh = *(const bf16x8*)&g1hi[bidx * 8];
      bf16x8 bl = *(const bf16x8*)&g1lo[bidx * 8];
#pragma unroll
      for (int mtl = 0; mtl < 2; ++mtl) {
        acc[mtl][nt] = MFMA16(ah[mtl], bh, acc[mtl][nt]);
        acc[mtl][nt] = MFMA16(al[mtl], bh, acc[mtl][nt]);
        acc[mtl][nt] = MFMA16(ah[mtl], bl, acc[mtl][nt]);
      }
    }
  }

  // epilogue: silu + project to 4 heads; lane ln holds hidden col n=nt*16+ln
  float p[2][4][4];
#pragma unroll
  for (int mtl = 0; mtl < 2; ++mtl)
#pragma unroll
    for (int reg = 0; reg < 4; ++reg)
#pragma unroll
      for (int hh = 0; hh < 4; ++hh) p[mtl][reg][hh] = 0.f;
#pragma unroll
  for (int nt = 0; nt < 8; ++nt) {
    int n = nt * 16 + ln;
    float b1v = bg1[n];
    float4 w2 = *(const float4*)&Wg2[n * 4];
#pragma unroll
    for (int mtl = 0; mtl < 2; ++mtl)
#pragma unroll
      for (int reg = 0; reg < 4; ++reg) {
        float h = acc[mtl][nt][reg] + b1v;
        float s = h / (1.f + __expf(-h));
        p[mtl][reg][0] = fmaf(s, w2.x, p[mtl][reg][0]);
        p[mtl][reg][1] = fmaf(s, w2.y, p[mtl][reg][1]);
        p[mtl][reg][2] = fmaf(s, w2.z, p[mtl][reg][2]);
        p[mtl][reg][3] = fmaf(s, w2.w, p[mtl][reg][3]);
      }
  }
#pragma unroll
  for (int off = 1; off < 16; off <<= 1)
#pragma unroll
    for (int mtl = 0; mtl < 2; ++mtl)
#pragma unroll
      for (int reg = 0; reg < 4; ++reg)
#pragma unroll
        for (int hh = 0; hh < 4; ++hh)
          p[mtl][reg][hh] += __shfl_xor(p[mtl][reg][hh], off, 64);
#pragma unroll
  for (int mtl = 0; mtl < 2; ++mtl) {
    float v = 0.f;
#pragma unroll
    for (int reg = 0; reg < 4; ++reg)
#pragma unroll
      for (int hh = 0; hh < 4; ++hh)
        if (ln == reg * 4 + hh) v = p[mtl][reg][hh];
    int reg = ln >> 2, hh = ln & 3;
    int e = e0 + (mtb + mtl) * 16 + lq * 4 + reg;
    if (e < NE) {
      int code = isd[srcv[e]] * 2 + isd[dstv[e]];
      biasE[e * 4 + hh] = v + bg2[hh] + db[hh * 4 + code];
    }
  }
}

// --------------------------- CSR build ------------------------------------
__global__ void k_count(const int* __restrict__ dstv, int* __restrict__ cnt) {
  int e = blockIdx.x * 256 + threadIdx.x;
  if (e < NE) atomicAdd(&cnt[dstv[e]], 1);
}

__global__ void k_scan1(const int* __restrict__ cnt, int* __restrict__ bsum) {
  __shared__ int sd[256];
  int t = threadIdx.x;
  int i = blockIdx.x * 256 + t;
  sd[t] = (i < NN) ? cnt[i] : 0;
  __syncthreads();
  for (int off = 128; off > 0; off >>= 1) {
    if (t < off) sd[t] += sd[t + off];
    __syncthreads();
  }
  if (t == 0) bsum[blockIdx.x] = sd[0];
}

__global__ void k_scan2(const int* __restrict__ bsum, int* __restrict__ bpre,
                        int* __restrict__ offsets, int nb) {
  __shared__ int sd[256];
  int t = threadIdx.x;
  int v = (t < nb) ? bsum[t] : 0;
  sd[t] = v;
  __syncthreads();
  for (int off = 1; off < 256; off <<= 1) {
    int x = (t >= off) ? sd[t - off] : 0;
    __syncthreads();
    sd[t] += x;
    __syncthreads();
  }
  if (t < nb) bpre[t] = sd[t] - v;
  if (t == 255) offsets[NN] = sd[255];
}

__global__ void k_scan3(const int* __restrict__ cnt, const int* __restrict__ bpre,
                        int* __restrict__ offsets, int* __restrict__ cursor) {
  __shared__ int sd[256];
  int t = threadIdx.x;
  int i = blockIdx.x * 256 + t;
  int v = (i < NN) ? cnt[i] : 0;
  sd[t] = v;
  __syncthreads();
  for (int off = 1; off < 256; off <<= 1) {
    int x = (t >= off) ? sd[t - off] : 0;
    __syncthreads();
    sd[t] += x;
    __syncthreads();
  }
  int excl = sd[t] - v + bpre[blockIdx.x];
  if (i < NN) { offsets[i] = excl; cursor[i] = excl; }
}

// scatter: also records srcCSR so the hot loop reads contiguously
__global__ void k_scatter(const int* __restrict__ srcv,
                          const int* __restrict__ dstv,
                          int* __restrict__ cursor,
                          int* __restrict__ eids, int* __restrict__ srcCSR) {
  int e = blockIdx.x * 256 + threadIdx.x;
  if (e < NE) {
    int d = dstv[e];
    int pos = atomicAdd(&cursor[d], 1);
    eids[pos] = e;
    srcCSR[pos] = srcv[e];
  }
}

// ---------------------------------------------------------------------------
// FUSED per-dst: QK^T score + bias + ONLINE softmax + V aggregation.
// One 128-thread block per node; thread t = (head t>>5, dim t&31).
// K[dst] is loop-invariant: each thread holds its K element in a register.
// Per edge: gather Q/V rows (coalesced 512B), 5-step shfl dot-reduce,
// online max/denom/acc update. Single pass, no score round-trip.
// ---------------------------------------------------------------------------
__global__ __launch_bounds__(128) void k_agg_fused(
    const int* __restrict__ srcCSR, const int* __restrict__ eids,
    const int* __restrict__ offsets, const float* __restrict__ biasE,
    const float* __restrict__ Q, const float* __restrict__ K,
    const float* __restrict__ V, float* __restrict__ accum) {
  int b = blockIdx.x;
  int t = threadIdx.x;
  int h = t >> 5;
  int beg = offsets[b], end = offsets[b + 1];
  float kv = K[b * HID + t];  // this thread's K[dst] element

  float m = -3.0e38f, den = 0.f, acc = 0.f;
  int s_n = (beg < end) ? srcCSR[beg] : 0;
  int e_n = (beg < end) ? eids[beg] : 0;
  for (int i = beg; i < end; ++i) {
    int s = s_n, e = e_n;
    if (i + 1 < end) {  // uniform branch; prefetch next indices
      s_n = srcCSR[i + 1];
      e_n = eids[i + 1];
    }
    float qv = Q[s * HID + t];
    float vv = V[s * HID + t];
    float bias = biasE[e * 4 + h];
    float prod = qv * kv;
#pragma unroll
    for (int off = 1; off < 32; off <<= 1)
      prod += __shfl_xor(prod, off, 32);  // 32-dim head dot product
    float sc = fmaf(prod, SCALE, bias);
    float mn = fmaxf(m, sc);
    float r = __expf(m - mn);   // 1 when max unchanged; 0 on first edge
    float w = __expf(sc - mn);
    den = fmaf(den, r, w);
    acc = fmaf(acc, r, w * vv);
    m = mn;
  }
  accum[b * HID + t] = (end > beg) ? (acc / den) : 0.f;
}

// ---------------------------------------------------------------------------
extern "C" void kernel_launch(void* const* d_in, const int* in_sizes, int n_in,
                              void* d_out, int out_size, void* d_ws, size_t ws_size,
                              hipStream_t stream) {
  const float* x = (const float*)d_in[0];
  const int* ei = (const int*)d_in[1];
  const float* rbf = (const float*)d_in[2];
  const int* isd = (const int*)d_in[3];
  const float* Wq = (const float*)d_in[4];
  const float* bq = (const float*)d_in[5];
  const float* Wk = (const float*)d_in[6];
  const float* bk = (const float*)d_in[7];
  const float* Wv = (const float*)d_in[8];
  const float* bv = (const float*)d_in[9];
  const float* Wo = (const float*)d_in[10];
  const float* bo = (const float*)d_in[11];
  const float* Wg1 = (const float*)d_in[12];
  const float* bg1 = (const float*)d_in[13];
  const float* Wg2 = (const float*)d_in[14];
  const float* bg2 = (const float*)d_in[15];
  const float* db = (const float*)d_in[16];
  const int* srcv = ei;
  const int* dstv = ei + NE;

  char* p = (char*)d_ws;
  auto alloc = [&](size_t bytes) {
    void* r = (void*)p;
    p += (bytes + 255) & ~(size_t)255;
    return r;
  };
  float* Q = (float*)alloc((size_t)NN * HID * 4);
  float* Kb = (float*)alloc((size_t)NN * HID * 4);
  float* Vb = (float*)alloc((size_t)NN * HID * 4);
  float* biasE = (float*)alloc((size_t)NE * NH * 4);
  float* accum = (float*)alloc((size_t)NN * HID * 4);
  int* cnt = (int*)alloc((size_t)NN * 4);
  int* offsets = (int*)alloc((size_t)(NN + 1) * 4);
  int* cursor = (int*)alloc((size_t)NN * 4);
  int* eids = (int*)alloc((size_t)NE * 4);
  int* srcCSR = (int*)alloc((size_t)NE * 4);
  int* bsum = (int*)alloc(256 * 4);
  int* bpre = (int*)alloc(256 * 4);
  // split-bf16 weight frag buffers
  __bf16* qhi = (__bf16*)alloc(2048 * 8 * 2);
  __bf16* qlo = (__bf16*)alloc(2048 * 8 * 2);
  __bf16* khi = (__bf16*)alloc(2048 * 8 * 2);
  __bf16* klo = (__bf16*)alloc(2048 * 8 * 2);
  __bf16* vhi = (__bf16*)alloc(2048 * 8 * 2);
  __bf16* vlo = (__bf16*)alloc(2048 * 8 * 2);
  __bf16* ohi = (__bf16*)alloc(2048 * 8 * 2);
  __bf16* olo = (__bf16*)alloc(2048 * 8 * 2);
  __bf16* g1hi = (__bf16*)alloc(1024 * 8 * 2);
  __bf16* g1lo = (__bf16*)alloc(1024 * 8 * 2);

  hipMemsetAsync(cnt, 0, (size_t)NN * 4, stream);

  int gQ = (NN + 127) / 128;       // 391
  int gE = (NE + 127) / 128;       // 4688
  int gEth = (NE + 255) / 256;     // 2344
  int gS = (NN + 255) / 256;       // 196

  k_prepw<<<8, 256, 0, stream>>>(Wq, qhi, qlo, 4, 128);
  k_prepw<<<8, 256, 0, stream>>>(Wk, khi, klo, 4, 128);
  k_prepw<<<8, 256, 0, stream>>>(Wv, vhi, vlo, 4, 128);
  k_prepw<<<8, 256, 0, stream>>>(Wo, ohi, olo, 4, 128);
  k_prepw<<<4, 256, 0, stream>>>(Wg1, g1hi, g1lo, 2, NRBF);

  k_qkv3<<<gQ, 256, 0, stream>>>(x, qhi, qlo, khi, klo, vhi, vlo,
                                 bq, bk, bv, Q, Kb, Vb, NN);
  k_geo_mfma<<<gE, 256, 0, stream>>>(rbf, g1hi, g1lo, bg1, Wg2, bg2,
                                     srcv, dstv, isd, db, biasE);
  k_count<<<gEth, 256, 0, stream>>>(dstv, cnt);
  k_scan1<<<gS, 256, 0, stream>>>(cnt, bsum);
  k_scan2<<<1, 256, 0, stream>>>(bsum, bpre, offsets, gS);
  k_scan3<<<gS, 256, 0, stream>>>(cnt, bpre, offsets, cursor);
  k_scatter<<<gEth, 256, 0, stream>>>(srcv, dstv, cursor, eids, srcCSR);
  k_agg_fused<<<NN, 128, 0, stream>>>(srcCSR, eids, offsets, biasE,
                                      Q, Kb, Vb, accum);
  k_mm128<<<gQ, 256, 0, stream>>>(accum, ohi, olo, bo, (float*)d_out, NN);
}

// Round 12
// 488.478 us; speedup vs baseline: 1.4791x; 1.0174x over previous
//
#include <hip/hip_runtime.h>
#include <math.h>

#define NN 50000
#define NE 600000
#define HID 128
#define NH 4
#define HD 32
#define NRBF 40
#define SCALE 0.17677669529663687f  // 1/sqrt(32)

typedef __attribute__((ext_vector_type(8))) __bf16 bf16x8;
typedef __attribute__((ext_vector_type(4))) __bf16 bf16x4;
typedef __attribute__((ext_vector_type(4))) float f32x4;

#define MFMA16(a, b, c) __builtin_amdgcn_mfma_f32_16x16x32_bf16(a, b, c, 0, 0, 0)

__device__ __forceinline__ void split2(float v, __bf16& h, __bf16& l) {
  h = (__bf16)v;          // RNE round to bf16
  l = (__bf16)(v - (float)h);  // residual, also bf16: total ~2^-17 rel err
}

// ---------------------------------------------------------------------------
// Weight prep: convert W[K x 128] fp32 into MFMA B-frag ordered hi/lo bf16.
// Slot = ((nt*NKS + ks)*4 + kg)*16 + n holds 8 bf16: W[ks*32+kg*8+j][nt*16+n],
// zero-padded for k >= KREAL.
// ---------------------------------------------------------------------------
__global__ void k_prepw(const float* __restrict__ W, __bf16* __restrict__ hi,
                        __bf16* __restrict__ lo, int NKS, int KREAL) {
  int slot = blockIdx.x * 256 + threadIdx.x;
  int total = 8 * NKS * 4 * 16;
  if (slot >= total) return;
  int n = slot & 15, kg = (slot >> 4) & 3;
  int tt = slot >> 6;
  int ks = tt % NKS, nt = tt / NKS;
  bf16x8 h8, l8;
#pragma unroll
  for (int j = 0; j < 8; ++j) {
    int k = ks * 32 + kg * 8 + j;
    float v = (k < KREAL) ? W[k * 128 + nt * 16 + n] : 0.f;
    __bf16 h, l;
    split2(v, h, l);
    h8[j] = h;
    l8[j] = l;
  }
  *(bf16x8*)&hi[slot * 8] = h8;
  *(bf16x8*)&lo[slot * 8] = l8;
}

// ---------------------------------------------------------------------------
// Fused QKV.  Q,V written as bf16 (feed only the gather kernel); K as fp32.
// ---------------------------------------------------------------------------
__global__ __launch_bounds__(256) void k_qkv3(
    const float* __restrict__ x,
    const __bf16* __restrict__ qhi, const __bf16* __restrict__ qlo,
    const __bf16* __restrict__ khi, const __bf16* __restrict__ klo,
    const __bf16* __restrict__ vhi, const __bf16* __restrict__ vlo,
    const float* __restrict__ bq, const float* __restrict__ bk,
    const float* __restrict__ bv,
    __bf16* __restrict__ Qb, float* __restrict__ K, __bf16* __restrict__ Vb,
    int M) {
  __shared__ __bf16 Ahi[16384];  // slot(mt,ks,kg,m)*8 ; 32KB
  __shared__ __bf16 Alo[16384];
  int t = threadIdx.x;
  int row0 = blockIdx.x * 128;

#pragma unroll
  for (int rep = 0; rep < 16; ++rep) {
    int idx = rep * 256 + t;
    int e = idx >> 5, c = idx & 31;
    int gn = row0 + e;
    float4 a = (gn < M) ? *(const float4*)&x[gn * 128 + c * 4]
                        : make_float4(0.f, 0.f, 0.f, 0.f);
    int mt = e >> 4, m = e & 15, ks = c >> 3, kg = (c >> 1) & 3, half = c & 1;
    int base = ((((mt * 4 + ks) * 4 + kg) * 16) + m) * 8 + half * 4;
    bf16x4 h4, l4;
    __bf16 h, l;
    split2(a.x, h, l); h4[0] = h; l4[0] = l;
    split2(a.y, h, l); h4[1] = h; l4[1] = l;
    split2(a.z, h, l); h4[2] = h; l4[2] = l;
    split2(a.w, h, l); h4[3] = h; l4[3] = l;
    *(bf16x4*)&Ahi[base] = h4;
    *(bf16x4*)&Alo[base] = l4;
  }
  __syncthreads();

  int wave = t >> 6, l = t & 63;
  int lq = l >> 4, ln = l & 15;
  int nt0 = wave * 2;
  const __bf16* whi[3] = {qhi, khi, vhi};
  const __bf16* wlo[3] = {qlo, klo, vlo};
  const float* bias[3] = {bq, bk, bv};
  const f32x4 fz = {0.f, 0.f, 0.f, 0.f};

#pragma unroll
  for (int w = 0; w < 3; ++w) {
    bf16x8 Bh[2][4], Bl[2][4];
#pragma unroll
    for (int ntl = 0; ntl < 2; ++ntl)
#pragma unroll
      for (int ks = 0; ks < 4; ++ks) {
        int bidx = (((nt0 + ntl) * 4 + ks) * 4 + lq) * 16 + ln;
        Bh[ntl][ks] = *(const bf16x8*)&whi[w][bidx * 8];
        Bl[ntl][ks] = *(const bf16x8*)&wlo[w][bidx * 8];
      }
    f32x4 acc[8][2];
#pragma unroll
    for (int mt = 0; mt < 8; ++mt) { acc[mt][0] = fz; acc[mt][1] = fz; }
#pragma unroll
    for (int mt = 0; mt < 8; ++mt)
#pragma unroll
      for (int ks = 0; ks < 4; ++ks) {
        int as = ((((mt * 4 + ks) * 4 + lq) * 16) + ln) * 8;
        bf16x8 ah = *(bf16x8*)&Ahi[as];
        bf16x8 al = *(bf16x8*)&Alo[as];
#pragma unroll
        for (int ntl = 0; ntl < 2; ++ntl) {
          acc[mt][ntl] = MFMA16(ah, Bh[ntl][ks], acc[mt][ntl]);
          acc[mt][ntl] = MFMA16(al, Bh[ntl][ks], acc[mt][ntl]);
          acc[mt][ntl] = MFMA16(ah, Bl[ntl][ks], acc[mt][ntl]);
        }
      }
    int n0 = nt0 * 16 + ln;
    float b0 = bias[w][n0], b1 = bias[w][n0 + 16];
#pragma unroll
    for (int mt = 0; mt < 8; ++mt)
#pragma unroll
      for (int reg = 0; reg < 4; ++reg) {
        int e = row0 + mt * 16 + lq * 4 + reg;
        if (e < M) {
          float v0 = acc[mt][0][reg] + b0;
          float v1 = acc[mt][1][reg] + b1;
          if (w == 1) {  // K: fp32
            K[e * 128 + n0] = v0;
            K[e * 128 + n0 + 16] = v1;
          } else {       // Q, V: bf16
            __bf16* dst = (w == 0) ? Qb : Vb;
            dst[e * 128 + n0] = (__bf16)v0;
            dst[e * 128 + n0 + 16] = (__bf16)v1;
          }
        }
      }
  }
}

// ---------------------------------------------------------------------------
// Output projection: out[M,128] = A @ W + b, split-bf16, fp32 out.
// ---------------------------------------------------------------------------
__global__ __launch_bounds__(256) void k_mm128(
    const float* __restrict__ A, const __bf16* __restrict__ whi,
    const __bf16* __restrict__ wlo, const float* __restrict__ bias,
    float* __restrict__ out, int M) {
  __shared__ __bf16 Ahi[16384];
  __shared__ __bf16 Alo[16384];
  int t = threadIdx.x;
  int row0 = blockIdx.x * 128;
#pragma unroll
  for (int rep = 0; rep < 16; ++rep) {
    int idx = rep * 256 + t;
    int e = idx >> 5, c = idx & 31;
    int gn = row0 + e;
    float4 a = (gn < M) ? *(const float4*)&A[gn * 128 + c * 4]
                        : make_float4(0.f, 0.f, 0.f, 0.f);
    int mt = e >> 4, m = e & 15, ks = c >> 3, kg = (c >> 1) & 3, half = c & 1;
    int base = ((((mt * 4 + ks) * 4 + kg) * 16) + m) * 8 + half * 4;
    bf16x4 h4, l4;
    __bf16 h, l;
    split2(a.x, h, l); h4[0] = h; l4[0] = l;
    split2(a.y, h, l); h4[1] = h; l4[1] = l;
    split2(a.z, h, l); h4[2] = h; l4[2] = l;
    split2(a.w, h, l); h4[3] = h; l4[3] = l;
    *(bf16x4*)&Ahi[base] = h4;
    *(bf16x4*)&Alo[base] = l4;
  }
  __syncthreads();

  int wave = t >> 6, l = t & 63;
  int lq = l >> 4, ln = l & 15;
  int nt0 = wave * 2;
  const f32x4 fz = {0.f, 0.f, 0.f, 0.f};
  bf16x8 Bh[2][4], Bl[2][4];
#pragma unroll
  for (int ntl = 0; ntl < 2; ++ntl)
#pragma unroll
    for (int ks = 0; ks < 4; ++ks) {
      int bidx = (((nt0 + ntl) * 4 + ks) * 4 + lq) * 16 + ln;
      Bh[ntl][ks] = *(const bf16x8*)&whi[bidx * 8];
      Bl[ntl][ks] = *(const bf16x8*)&wlo[bidx * 8];
    }
  f32x4 acc[8][2];
#pragma unroll
  for (int mt = 0; mt < 8; ++mt) { acc[mt][0] = fz; acc[mt][1] = fz; }
#pragma unroll
  for (int mt = 0; mt < 8; ++mt)
#pragma unroll
    for (int ks = 0; ks < 4; ++ks) {
      int as = ((((mt * 4 + ks) * 4 + lq) * 16) + ln) * 8;
      bf16x8 ah = *(bf16x8*)&Ahi[as];
      bf16x8 al = *(bf16x8*)&Alo[as];
#pragma unroll
      for (int ntl = 0; ntl < 2; ++ntl) {
        acc[mt][ntl] = MFMA16(ah, Bh[ntl][ks], acc[mt][ntl]);
        acc[mt][ntl] = MFMA16(al, Bh[ntl][ks], acc[mt][ntl]);
        acc[mt][ntl] = MFMA16(ah, Bl[ntl][ks], acc[mt][ntl]);
      }
    }
  int n0 = nt0 * 16 + ln;
  float b0 = bias[n0], b1 = bias[n0 + 16];
#pragma unroll
  for (int mt = 0; mt < 8; ++mt)
#pragma unroll
    for (int reg = 0; reg < 4; ++reg) {
      int e = row0 + mt * 16 + lq * 4 + reg;
      if (e < M) {
        out[e * 128 + n0] = acc[mt][0][reg] + b0;
        out[e * 128 + n0 + 16] = acc[mt][1][reg] + b1;
      }
    }
}

// ---------------------------------------------------------------------------
// geo+defect bias via MFMA: hi-only rbf staging (16KB LDS, single cvt), Wg1
// kept split (Ah*Bh + Ah*Bl).  Staging index XOR-swizzled (m^kg) so the 8B
// writes spread across banks (was bank=(m*4+half*2): kg dropped out mod 32
// -> 5-way conflict, 2.85M cycles measured in r10).  Read side: ln^lq.
// ---------------------------------------------------------------------------
__global__ __launch_bounds__(256) void k_geo_mfma(
    const float* __restrict__ rbf, const __bf16* __restrict__ g1hi,
    const __bf16* __restrict__ g1lo, const float* __restrict__ bg1,
    const float* __restrict__ Wg2, const float* __restrict__ bg2,
    const int* __restrict__ srcv, const int* __restrict__ dstv,
    const int* __restrict__ isd, const float* __restrict__ db,
    float* __restrict__ biasE) {
  __shared__ __bf16 Ahi[8192];  // 16KB, slot(mt,ks,kg, m^kg)*8
  int t = threadIdx.x;
  int e0 = blockIdx.x * 128;

  bf16x8 zz = {};
#pragma unroll
  for (int z = 0; z < 4; ++z) *(bf16x8*)&Ahi[(z * 256 + t) * 8] = zz;
  __syncthreads();
#pragma unroll
  for (int rep = 0; rep < 5; ++rep) {
    int idx = rep * 256 + t;
    int e = idx / 10, c = idx % 10;
    int ge = e0 + e;
    float4 a = (ge < NE) ? *(const float4*)&rbf[ge * NRBF + c * 4]
                         : make_float4(0.f, 0.f, 0.f, 0.f);
    int k4 = c * 4;
    int mt = e >> 4, m = e & 15, ks = k4 >> 5, kg = (k4 >> 3) & 3,
        half = (k4 >> 2) & 1;
    int base = ((((mt * 2 + ks) * 4 + kg) * 16) + (m ^ kg)) * 8 + half * 4;
    bf16x4 h4;
    h4[0] = (__bf16)a.x;
    h4[1] = (__bf16)a.y;
    h4[2] = (__bf16)a.z;
    h4[3] = (__bf16)a.w;
    *(bf16x4*)&Ahi[base] = h4;
  }
  __syncthreads();

  int wave = t >> 6, l = t & 63;
  int lq = l >> 4, ln = l & 15;
  int mtb = wave * 2;
  const f32x4 fz = {0.f, 0.f, 0.f, 0.f};
  f32x4 acc[2][8];
#pragma unroll
  for (int mtl = 0; mtl < 2; ++mtl)
#pragma unroll
    for (int nt = 0; nt < 8; ++nt) acc[mtl][nt] = fz;

#pragma unroll
  for (int ks = 0; ks < 2; ++ks) {
    bf16x8 ah[2];
#pragma unroll
    for (int mtl = 0; mtl < 2; ++mtl) {
      int as = (((((mtb + mtl) * 2 + ks) * 4 + lq) * 16) + (ln ^ lq)) * 8;
      ah[mtl] = *(bf16x8*)&Ahi[as];
    }
#pragma unroll
    for (int nt = 0; nt < 8; ++nt) {
      int bidx = ((nt * 2 + ks) * 4 + lq) * 16 + ln;
      bf16x8 bh = *(const bf16x8*)&g1hi[bidx * 8];
      bf16x8 bl = *(const bf16x8*)&g1lo[bidx * 8];
#pragma unroll
      for (int mtl = 0; mtl < 2; ++mtl) {
        acc[mtl][nt] = MFMA16(ah[mtl], bh, acc[mtl][nt]);
        acc[mtl][nt] = MFMA16(ah[mtl], bl, acc[mtl][nt]);
      }
    }
  }

  // epilogue: silu + project to 4 heads; lane ln holds hidden col n=nt*16+ln
  float p[2][4][4];
#pragma unroll
  for (int mtl = 0; mtl < 2; ++mtl)
#pragma unroll
    for (int reg = 0; reg < 4; ++reg)
#pragma unroll
      for (int hh = 0; hh < 4; ++hh) p[mtl][reg][hh] = 0.f;
#pragma unroll
  for (int nt = 0; nt < 8; ++nt) {
    int n = nt * 16 + ln;
    float b1v = bg1[n];
    float4 w2 = *(const float4*)&Wg2[n * 4];
#pragma unroll
    for (int mtl = 0; mtl < 2; ++mtl)
#pragma unroll
      for (int reg = 0; reg < 4; ++reg) {
        float h = acc[mtl][nt][reg] + b1v;
        float s = h / (1.f + __expf(-h));
        p[mtl][reg][0] = fmaf(s, w2.x, p[mtl][reg][0]);
        p[mtl][reg][1] = fmaf(s, w2.y, p[mtl][reg][1]);
        p[mtl][reg][2] = fmaf(s, w2.z, p[mtl][reg][2]);
        p[mtl][reg][3] = fmaf(s, w2.w, p[mtl][reg][3]);
      }
  }
#pragma unroll
  for (int off = 1; off < 16; off <<= 1)
#pragma unroll
    for (int mtl = 0; mtl < 2; ++mtl)
#pragma unroll
      for (int reg = 0; reg < 4; ++reg)
#pragma unroll
        for (int hh = 0; hh < 4; ++hh)
          p[mtl][reg][hh] += __shfl_xor(p[mtl][reg][hh], off, 64);
#pragma unroll
  for (int mtl = 0; mtl < 2; ++mtl) {
    float v = 0.f;
#pragma unroll
    for (int reg = 0; reg < 4; ++reg)
#pragma unroll
      for (int hh = 0; hh < 4; ++hh)
        if (ln == reg * 4 + hh) v = p[mtl][reg][hh];
    int reg = ln >> 2, hh = ln & 3;
    int e = e0 + (mtb + mtl) * 16 + lq * 4 + reg;
    if (e < NE) {
      int code = isd[srcv[e]] * 2 + isd[dstv[e]];
      biasE[e * 4 + hh] = v + bg2[hh] + db[hh * 4 + code];
    }
  }
}

// --------------------------- CSR build ------------------------------------
__global__ void k_count(const int* __restrict__ dstv, int* __restrict__ cnt) {
  int e = blockIdx.x * 256 + threadIdx.x;
  if (e < NE) atomicAdd(&cnt[dstv[e]], 1);
}

__global__ void k_scan1(const int* __restrict__ cnt, int* __restrict__ bsum) {
  __shared__ int sd[256];
  int t = threadIdx.x;
  int i = blockIdx.x * 256 + t;
  sd[t] = (i < NN) ? cnt[i] : 0;
  __syncthreads();
  for (int off = 128; off > 0; off >>= 1) {
    if (t < off) sd[t] += sd[t + off];
    __syncthreads();
  }
  if (t == 0) bsum[blockIdx.x] = sd[0];
}

__global__ void k_scan2(const int* __restrict__ bsum, int* __restrict__ bpre,
                        int* __restrict__ offsets, int nb) {
  __shared__ int sd[256];
  int t = threadIdx.x;
  int v = (t < nb) ? bsum[t] : 0;
  sd[t] = v;
  __syncthreads();
  for (int off = 1; off < 256; off <<= 1) {
    int x = (t >= off) ? sd[t - off] : 0;
    __syncthreads();
    sd[t] += x;
    __syncthreads();
  }
  if (t < nb) bpre[t] = sd[t] - v;
  if (t == 255) offsets[NN] = sd[255];
}

__global__ void k_scan3(const int* __restrict__ cnt, const int* __restrict__ bpre,
                        int* __restrict__ offsets, int* __restrict__ cursor) {
  __shared__ int sd[256];
  int t = threadIdx.x;
  int i = blockIdx.x * 256 + t;
  int v = (i < NN) ? cnt[i] : 0;
  sd[t] = v;
  __syncthreads();
  for (int off = 1; off < 256; off <<= 1) {
    int x = (t >= off) ? sd[t - off] : 0;
    __syncthreads();
    sd[t] += x;
    __syncthreads();
  }
  int excl = sd[t] - v + bpre[blockIdx.x];
  if (i < NN) { offsets[i] = excl; cursor[i] = excl; }
}

__global__ void k_scatter(const int* __restrict__ srcv,
                          const int* __restrict__ dstv,
                          int* __restrict__ cursor,
                          int* __restrict__ eids, int* __restrict__ srcCSR) {
  int e = blockIdx.x * 256 + threadIdx.x;
  if (e < NE) {
    int d = dstv[e];
    int pos = atomicAdd(&cursor[d], 1);
    eids[pos] = e;
    srcCSR[pos] = srcv[e];
  }
}

// ---------------------------------------------------------------------------
// FUSED per-dst: QK^T + bias + online softmax + V aggregation.
// Q,V gathered as bf16 (half the r10 bytes); K[dst] fp32, loop-invariant.
// ---------------------------------------------------------------------------
__global__ __launch_bounds__(128) void k_agg_fused(
    const int* __restrict__ srcCSR, const int* __restrict__ eids,
    const int* __restrict__ offsets, const float* __restrict__ biasE,
    const __bf16* __restrict__ Qb, const float* __restrict__ K,
    const __bf16* __restrict__ Vb, float* __restrict__ accum) {
  int b = blockIdx.x;
  int t = threadIdx.x;
  int h = t >> 5;
  int beg = offsets[b], end = offsets[b + 1];
  float kv = K[b * HID + t];  // this thread's K[dst] element

  float m = -3.0e38f, den = 0.f, acc = 0.f;
  int s_n = (beg < end) ? srcCSR[beg] : 0;
  int e_n = (beg < end) ? eids[beg] : 0;
  for (int i = beg; i < end; ++i) {
    int s = s_n, e = e_n;
    if (i + 1 < end) {  // uniform branch; prefetch next indices
      s_n = srcCSR[i + 1];
      e_n = eids[i + 1];
    }
    float qv = (float)Qb[s * HID + t];
    float vv = (float)Vb[s * HID + t];
    float bias = biasE[e * 4 + h];
    float prod = qv * kv;
#pragma unroll
    for (int off = 1; off < 32; off <<= 1)
      prod += __shfl_xor(prod, off, 32);  // 32-dim head dot product
    float sc = fmaf(prod, SCALE, bias);
    float mn = fmaxf(m, sc);
    float r = __expf(m - mn);
    float w = __expf(sc - mn);
    den = fmaf(den, r, w);
    acc = fmaf(acc, r, w * vv);
    m = mn;
  }
  accum[b * HID + t] = (end > beg) ? (acc / den) : 0.f;
}

// ---------------------------------------------------------------------------
extern "C" void kernel_launch(void* const* d_in, const int* in_sizes, int n_in,
                              void* d_out, int out_size, void* d_ws, size_t ws_size,
                              hipStream_t stream) {
  const float* x = (const float*)d_in[0];
  const int* ei = (const int*)d_in[1];
  const float* rbf = (const float*)d_in[2];
  const int* isd = (const int*)d_in[3];
  const float* Wq = (const float*)d_in[4];
  const float* bq = (const float*)d_in[5];
  const float* Wk = (const float*)d_in[6];
  const float* bk = (const float*)d_in[7];
  const float* Wv = (const float*)d_in[8];
  const float* bv = (const float*)d_in[9];
  const float* Wo = (const float*)d_in[10];
  const float* bo = (const float*)d_in[11];
  const float* Wg1 = (const float*)d_in[12];
  const float* bg1 = (const float*)d_in[13];
  const float* Wg2 = (const float*)d_in[14];
  const float* bg2 = (const float*)d_in[15];
  const float* db = (const float*)d_in[16];
  const int* srcv = ei;
  const int* dstv = ei + NE;

  char* p = (char*)d_ws;
  auto alloc = [&](size_t bytes) {
    void* r = (void*)p;
    p += (bytes + 255) & ~(size_t)255;
    return r;
  };
  __bf16* Qb = (__bf16*)alloc((size_t)NN * HID * 2);
  float* Kb = (float*)alloc((size_t)NN * HID * 4);
  __bf16* Vb = (__bf16*)alloc((size_t)NN * HID * 2);
  float* biasE = (float*)alloc((size_t)NE * NH * 4);
  float* accum = (float*)alloc((size_t)NN * HID * 4);
  int* cnt = (int*)alloc((size_t)NN * 4);
  int* offsets = (int*)alloc((size_t)(NN + 1) * 4);
  int* cursor = (int*)alloc((size_t)NN * 4);
  int* eids = (int*)alloc((size_t)NE * 4);
  int* srcCSR = (int*)alloc((size_t)NE * 4);
  int* bsum = (int*)alloc(256 * 4);
  int* bpre = (int*)alloc(256 * 4);
  // split-bf16 weight frag buffers
  __bf16* qhi = (__bf16*)alloc(2048 * 8 * 2);
  __bf16* qlo = (__bf16*)alloc(2048 * 8 * 2);
  __bf16* khi = (__bf16*)alloc(2048 * 8 * 2);
  __bf16* klo = (__bf16*)alloc(2048 * 8 * 2);
  __bf16* vhi = (__bf16*)alloc(2048 * 8 * 2);
  __bf16* vlo = (__bf16*)alloc(2048 * 8 * 2);
  __bf16* ohi = (__bf16*)alloc(2048 * 8 * 2);
  __bf16* olo = (__bf16*)alloc(2048 * 8 * 2);
  __bf16* g1hi = (__bf16*)alloc(1024 * 8 * 2);
  __bf16* g1lo = (__bf16*)alloc(1024 * 8 * 2);

  hipMemsetAsync(cnt, 0, (size_t)NN * 4, stream);

  int gQ = (NN + 127) / 128;       // 391
  int gE = (NE + 127) / 128;       // 4688
  int gEth = (NE + 255) / 256;     // 2344
  int gS = (NN + 255) / 256;       // 196

  k_prepw<<<8, 256, 0, stream>>>(Wq, qhi, qlo, 4, 128);
  k_prepw<<<8, 256, 0, stream>>>(Wk, khi, klo, 4, 128);
  k_prepw<<<8, 256, 0, stream>>>(Wv, vhi, vlo, 4, 128);
  k_prepw<<<8, 256, 0, stream>>>(Wo, ohi, olo, 4, 128);
  k_prepw<<<4, 256, 0, stream>>>(Wg1, g1hi, g1lo, 2, NRBF);

  k_qkv3<<<gQ, 256, 0, stream>>>(x, qhi, qlo, khi, klo, vhi, vlo,
                                 bq, bk, bv, Qb, Kb, Vb, NN);
  k_geo_mfma<<<gE, 256, 0, stream>>>(rbf, g1hi, g1lo, bg1, Wg2, bg2,
                                     srcv, dstv, isd, db, biasE);
  k_count<<<gEth, 256, 0, stream>>>(dstv, cnt);
  k_scan1<<<gS, 256, 0, stream>>>(cnt, bsum);
  k_scan2<<<1, 256, 0, stream>>>(bsum, bpre, offsets, gS);
  k_scan3<<<gS, 256, 0, stream>>>(cnt, bpre, offsets, cursor);
  k_scatter<<<gEth, 256, 0, stream>>>(srcv, dstv, cursor, eids, srcCSR);
  k_agg_fused<<<NN, 128, 0, stream>>>(srcCSR, eids, offsets, biasE,
                                      Qb, Kb, Vb, accum);
  k_mm128<<<gQ, 256, 0, stream>>>(accum, ohi, olo, bo, (float*)d_out, NN);
}

// Round 15
// 436.619 us; speedup vs baseline: 1.6548x; 1.1188x over previous
//
#include <hip/hip_runtime.h>
#include <math.h>

#define NN 50000
#define NE 600000
#define HID 128
#define NH 4
#define HD 32
#define NRBF 40
#define SCALE 0.17677669529663687f  // 1/sqrt(32)

typedef __attribute__((ext_vector_type(8))) __bf16 bf16x8;
typedef __attribute__((ext_vector_type(4))) __bf16 bf16x4;
typedef __attribute__((ext_vector_type(4))) float f32x4;

#define MFMA16(a, b, c) __builtin_amdgcn_mfma_f32_16x16x32_bf16(a, b, c, 0, 0, 0)

__device__ __forceinline__ void split2(float v, __bf16& h, __bf16& l) {
  h = (__bf16)v;
  l = (__bf16)(v - (float)h);
}

// ---------------------------------------------------------------------------
// All weight preps in ONE launch. Blocks 0-7:Wq 8-15:Wk 16-23:Wv 24-31:Wo
// 32-35:Wg1(K=40,NKS=2). Slot layout as before.
// ---------------------------------------------------------------------------
__global__ void k_prepw_all(
    const float* __restrict__ Wq, const float* __restrict__ Wk,
    const float* __restrict__ Wv, const float* __restrict__ Wo,
    const float* __restrict__ Wg1,
    __bf16* __restrict__ qhi, __bf16* __restrict__ qlo,
    __bf16* __restrict__ khi, __bf16* __restrict__ klo,
    __bf16* __restrict__ vhi, __bf16* __restrict__ vlo,
    __bf16* __restrict__ ohi, __bf16* __restrict__ olo,
    __bf16* __restrict__ g1hi, __bf16* __restrict__ g1lo) {
  int bb = blockIdx.x;
  const float* W;
  __bf16 *hi, *lo;
  int NKS, KREAL, base;
  if (bb < 8)       { W = Wq;  hi = qhi;  lo = qlo;  NKS = 4; KREAL = 128; base = bb; }
  else if (bb < 16) { W = Wk;  hi = khi;  lo = klo;  NKS = 4; KREAL = 128; base = bb - 8; }
  else if (bb < 24) { W = Wv;  hi = vhi;  lo = vlo;  NKS = 4; KREAL = 128; base = bb - 16; }
  else if (bb < 32) { W = Wo;  hi = ohi;  lo = olo;  NKS = 4; KREAL = 128; base = bb - 24; }
  else              { W = Wg1; hi = g1hi; lo = g1lo; NKS = 2; KREAL = NRBF; base = bb - 32; }
  int slot = base * 256 + threadIdx.x;
  int total = 8 * NKS * 4 * 16;
  if (slot >= total) return;
  int n = slot & 15, kg = (slot >> 4) & 3;
  int tt = slot >> 6;
  int ks = tt % NKS, nt = tt / NKS;
  bf16x8 h8, l8;
#pragma unroll
  for (int j = 0; j < 8; ++j) {
    int k = ks * 32 + kg * 8 + j;
    float v = (k < KREAL) ? W[k * 128 + nt * 16 + n] : 0.f;
    __bf16 h, l;
    split2(v, h, l);
    h8[j] = h;
    l8[j] = l;
  }
  *(bf16x8*)&hi[slot * 8] = h8;
  *(bf16x8*)&lo[slot * 8] = l8;
}

// ---------------------------------------------------------------------------
// Fused QKV.  Q,V written as bf16; K fp32.
// ---------------------------------------------------------------------------
__global__ __launch_bounds__(256) void k_qkv3(
    const float* __restrict__ x,
    const __bf16* __restrict__ qhi, const __bf16* __restrict__ qlo,
    const __bf16* __restrict__ khi, const __bf16* __restrict__ klo,
    const __bf16* __restrict__ vhi, const __bf16* __restrict__ vlo,
    const float* __restrict__ bq, const float* __restrict__ bk,
    const float* __restrict__ bv,
    __bf16* __restrict__ Qb, float* __restrict__ K, __bf16* __restrict__ Vb,
    int M) {
  __shared__ __bf16 Ahi[16384];
  __shared__ __bf16 Alo[16384];
  int t = threadIdx.x;
  int row0 = blockIdx.x * 128;

#pragma unroll
  for (int rep = 0; rep < 16; ++rep) {
    int idx = rep * 256 + t;
    int e = idx >> 5, c = idx & 31;
    int gn = row0 + e;
    float4 a = (gn < M) ? *(const float4*)&x[gn * 128 + c * 4]
                        : make_float4(0.f, 0.f, 0.f, 0.f);
    int mt = e >> 4, m = e & 15, ks = c >> 3, kg = (c >> 1) & 3, half = c & 1;
    int base = ((((mt * 4 + ks) * 4 + kg) * 16) + m) * 8 + half * 4;
    bf16x4 h4, l4;
    __bf16 h, l;
    split2(a.x, h, l); h4[0] = h; l4[0] = l;
    split2(a.y, h, l); h4[1] = h; l4[1] = l;
    split2(a.z, h, l); h4[2] = h; l4[2] = l;
    split2(a.w, h, l); h4[3] = h; l4[3] = l;
    *(bf16x4*)&Ahi[base] = h4;
    *(bf16x4*)&Alo[base] = l4;
  }
  __syncthreads();

  int wave = t >> 6, l = t & 63;
  int lq = l >> 4, ln = l & 15;
  int nt0 = wave * 2;
  const __bf16* whi[3] = {qhi, khi, vhi};
  const __bf16* wlo[3] = {qlo, klo, vlo};
  const float* bias[3] = {bq, bk, bv};
  const f32x4 fz = {0.f, 0.f, 0.f, 0.f};

#pragma unroll
  for (int w = 0; w < 3; ++w) {
    bf16x8 Bh[2][4], Bl[2][4];
#pragma unroll
    for (int ntl = 0; ntl < 2; ++ntl)
#pragma unroll
      for (int ks = 0; ks < 4; ++ks) {
        int bidx = (((nt0 + ntl) * 4 + ks) * 4 + lq) * 16 + ln;
        Bh[ntl][ks] = *(const bf16x8*)&whi[w][bidx * 8];
        Bl[ntl][ks] = *(const bf16x8*)&wlo[w][bidx * 8];
      }
    f32x4 acc[8][2];
#pragma unroll
    for (int mt = 0; mt < 8; ++mt) { acc[mt][0] = fz; acc[mt][1] = fz; }
#pragma unroll
    for (int mt = 0; mt < 8; ++mt)
#pragma unroll
      for (int ks = 0; ks < 4; ++ks) {
        int as = ((((mt * 4 + ks) * 4 + lq) * 16) + ln) * 8;
        bf16x8 ah = *(bf16x8*)&Ahi[as];
        bf16x8 al = *(bf16x8*)&Alo[as];
#pragma unroll
        for (int ntl = 0; ntl < 2; ++ntl) {
          acc[mt][ntl] = MFMA16(ah, Bh[ntl][ks], acc[mt][ntl]);
          acc[mt][ntl] = MFMA16(al, Bh[ntl][ks], acc[mt][ntl]);
          acc[mt][ntl] = MFMA16(ah, Bl[ntl][ks], acc[mt][ntl]);
        }
      }
    int n0 = nt0 * 16 + ln;
    float b0 = bias[w][n0], b1 = bias[w][n0 + 16];
#pragma unroll
    for (int mt = 0; mt < 8; ++mt)
#pragma unroll
      for (int reg = 0; reg < 4; ++reg) {
        int e = row0 + mt * 16 + lq * 4 + reg;
        if (e < M) {
          float v0 = acc[mt][0][reg] + b0;
          float v1 = acc[mt][1][reg] + b1;
          if (w == 1) {
            K[e * 128 + n0] = v0;
            K[e * 128 + n0 + 16] = v1;
          } else {
            __bf16* dst = (w == 0) ? Qb : Vb;
            dst[e * 128 + n0] = (__bf16)v0;
            dst[e * 128 + n0 + 16] = (__bf16)v1;
          }
        }
      }
  }
}

// ---------------------------------------------------------------------------
// Output projection: out[M,128] = A @ W + b, split-bf16, fp32 out.
// ---------------------------------------------------------------------------
__global__ __launch_bounds__(256) void k_mm128(
    const float* __restrict__ A, const __bf16* __restrict__ whi,
    const __bf16* __restrict__ wlo, const float* __restrict__ bias,
    float* __restrict__ out, int M) {
  __shared__ __bf16 Ahi[16384];
  __shared__ __bf16 Alo[16384];
  int t = threadIdx.x;
  int row0 = blockIdx.x * 128;
#pragma unroll
  for (int rep = 0; rep < 16; ++rep) {
    int idx = rep * 256 + t;
    int e = idx >> 5, c = idx & 31;
    int gn = row0 + e;
    float4 a = (gn < M) ? *(const float4*)&A[gn * 128 + c * 4]
                        : make_float4(0.f, 0.f, 0.f, 0.f);
    int mt = e >> 4, m = e & 15, ks = c >> 3, kg = (c >> 1) & 3, half = c & 1;
    int base = ((((mt * 4 + ks) * 4 + kg) * 16) + m) * 8 + half * 4;
    bf16x4 h4, l4;
    __bf16 h, l;
    split2(a.x, h, l); h4[0] = h; l4[0] = l;
    split2(a.y, h, l); h4[1] = h; l4[1] = l;
    split2(a.z, h, l); h4[2] = h; l4[2] = l;
    split2(a.w, h, l); h4[3] = h; l4[3] = l;
    *(bf16x4*)&Ahi[base] = h4;
    *(bf16x4*)&Alo[base] = l4;
  }
  __syncthreads();

  int wave = t >> 6, l = t & 63;
  int lq = l >> 4, ln = l & 15;
  int nt0 = wave * 2;
  const f32x4 fz = {0.f, 0.f, 0.f, 0.f};
  bf16x8 Bh[2][4], Bl[2][4];
#pragma unroll
  for (int ntl = 0; ntl < 2; ++ntl)
#pragma unroll
    for (int ks = 0; ks < 4; ++ks) {
      int bidx = (((nt0 + ntl) * 4 + ks) * 4 + lq) * 16 + ln;
      Bh[ntl][ks] = *(const bf16x8*)&whi[bidx * 8];
      Bl[ntl][ks] = *(const bf16x8*)&wlo[bidx * 8];
    }
  f32x4 acc[8][2];
#pragma unroll
  for (int mt = 0; mt < 8; ++mt) { acc[mt][0] = fz; acc[mt][1] = fz; }
#pragma unroll
  for (int mt = 0; mt < 8; ++mt)
#pragma unroll
    for (int ks = 0; ks < 4; ++ks) {
      int as = ((((mt * 4 + ks) * 4 + lq) * 16) + ln) * 8;
      bf16x8 ah = *(bf16x8*)&Ahi[as];
      bf16x8 al = *(bf16x8*)&Alo[as];
#pragma unroll
      for (int ntl = 0; ntl < 2; ++ntl) {
        acc[mt][ntl] = MFMA16(ah, Bh[ntl][ks], acc[mt][ntl]);
        acc[mt][ntl] = MFMA16(al, Bh[ntl][ks], acc[mt][ntl]);
        acc[mt][ntl] = MFMA16(ah, Bl[ntl][ks], acc[mt][ntl]);
      }
    }
  int n0 = nt0 * 16 + ln;
  float b0 = bias[n0], b1 = bias[n0 + 16];
#pragma unroll
  for (int mt = 0; mt < 8; ++mt)
#pragma unroll
    for (int reg = 0; reg < 4; ++reg) {
      int e = row0 + mt * 16 + lq * 4 + reg;
      if (e < M) {
        out[e * 128 + n0] = acc[mt][0][reg] + b0;
        out[e * 128 + n0 + 16] = acc[mt][1][reg] + b1;
      }
    }
}

// ---------------------------------------------------------------------------
// geo+defect bias via MFMA (hi-only rbf staging, m^kg swizzle) + folded
// dst-degree histogram (hh==0 lane: one atomic per edge; dstv[e] already
// loaded for the defect code).
// ---------------------------------------------------------------------------
__global__ __launch_bounds__(256) void k_geo_mfma(
    const float* __restrict__ rbf, const __bf16* __restrict__ g1hi,
    const __bf16* __restrict__ g1lo, const float* __restrict__ bg1,
    const float* __restrict__ Wg2, const float* __restrict__ bg2,
    const int* __restrict__ srcv, const int* __restrict__ dstv,
    const int* __restrict__ isd, const float* __restrict__ db,
    float* __restrict__ biasE, int* __restrict__ cnt) {
  __shared__ __bf16 Ahi[8192];
  int t = threadIdx.x;
  int e0 = blockIdx.x * 128;

  bf16x8 zz = {};
#pragma unroll
  for (int z = 0; z < 4; ++z) *(bf16x8*)&Ahi[(z * 256 + t) * 8] = zz;
  __syncthreads();
#pragma unroll
  for (int rep = 0; rep < 5; ++rep) {
    int idx = rep * 256 + t;
    int e = idx / 10, c = idx % 10;
    int ge = e0 + e;
    float4 a = (ge < NE) ? *(const float4*)&rbf[ge * NRBF + c * 4]
                         : make_float4(0.f, 0.f, 0.f, 0.f);
    int k4 = c * 4;
    int mt = e >> 4, m = e & 15, ks = k4 >> 5, kg = (k4 >> 3) & 3,
        half = (k4 >> 2) & 1;
    int base = ((((mt * 2 + ks) * 4 + kg) * 16) + (m ^ kg)) * 8 + half * 4;
    bf16x4 h4;
    h4[0] = (__bf16)a.x;
    h4[1] = (__bf16)a.y;
    h4[2] = (__bf16)a.z;
    h4[3] = (__bf16)a.w;
    *(bf16x4*)&Ahi[base] = h4;
  }
  __syncthreads();

  int wave = t >> 6, l = t & 63;
  int lq = l >> 4, ln = l & 15;
  int mtb = wave * 2;
  const f32x4 fz = {0.f, 0.f, 0.f, 0.f};
  f32x4 acc[2][8];
#pragma unroll
  for (int mtl = 0; mtl < 2; ++mtl)
#pragma unroll
    for (int nt = 0; nt < 8; ++nt) acc[mtl][nt] = fz;

#pragma unroll
  for (int ks = 0; ks < 2; ++ks) {
    bf16x8 ah[2];
#pragma unroll
    for (int mtl = 0; mtl < 2; ++mtl) {
      int as = (((((mtb + mtl) * 2 + ks) * 4 + lq) * 16) + (ln ^ lq)) * 8;
      ah[mtl] = *(bf16x8*)&Ahi[as];
    }
#pragma unroll
    for (int nt = 0; nt < 8; ++nt) {
      int bidx = ((nt * 2 + ks) * 4 + lq) * 16 + ln;
      bf16x8 bh = *(const bf16x8*)&g1hi[bidx * 8];
      bf16x8 bl = *(const bf16x8*)&g1lo[bidx * 8];
#pragma unroll
      for (int mtl = 0; mtl < 2; ++mtl) {
        acc[mtl][nt] = MFMA16(ah[mtl], bh, acc[mtl][nt]);
        acc[mtl][nt] = MFMA16(ah[mtl], bl, acc[mtl][nt]);
      }
    }
  }

  float p[2][4][4];
#pragma unroll
  for (int mtl = 0; mtl < 2; ++mtl)
#pragma unroll
    for (int reg = 0; reg < 4; ++reg)
#pragma unroll
      for (int hh = 0; hh < 4; ++hh) p[mtl][reg][hh] = 0.f;
#pragma unroll
  for (int nt = 0; nt < 8; ++nt) {
    int n = nt * 16 + ln;
    float b1v = bg1[n];
    float4 w2 = *(const float4*)&Wg2[n * 4];
#pragma unroll
    for (int mtl = 0; mtl < 2; ++mtl)
#pragma unroll
      for (int reg = 0; reg < 4; ++reg) {
        float h = acc[mtl][nt][reg] + b1v;
        float s = h / (1.f + __expf(-h));
        p[mtl][reg][0] = fmaf(s, w2.x, p[mtl][reg][0]);
        p[mtl][reg][1] = fmaf(s, w2.y, p[mtl][reg][1]);
        p[mtl][reg][2] = fmaf(s, w2.z, p[mtl][reg][2]);
        p[mtl][reg][3] = fmaf(s, w2.w, p[mtl][reg][3]);
      }
  }
#pragma unroll
  for (int off = 1; off < 16; off <<= 1)
#pragma unroll
    for (int mtl = 0; mtl < 2; ++mtl)
#pragma unroll
      for (int reg = 0; reg < 4; ++reg)
#pragma unroll
        for (int hh = 0; hh < 4; ++hh)
          p[mtl][reg][hh] += __shfl_xor(p[mtl][reg][hh], off, 64);
#pragma unroll
  for (int mtl = 0; mtl < 2; ++mtl) {
    float v = 0.f;
#pragma unroll
    for (int reg = 0; reg < 4; ++reg)
#pragma unroll
      for (int hh = 0; hh < 4; ++hh)
        if (ln == reg * 4 + hh) v = p[mtl][reg][hh];
    int reg = ln >> 2, hh = ln & 3;
    int e = e0 + (mtb + mtl) * 16 + lq * 4 + reg;
    if (e < NE) {
      int d = dstv[e];
      int code = isd[srcv[e]] * 2 + isd[d];
      biasE[e * 4 + hh] = v + bg2[hh] + db[hh * 4 + code];
      if (hh == 0) atomicAdd(&cnt[d], 1);  // folded k_count
    }
  }
}

// --------------------------- CSR build ------------------------------------
__global__ void k_scan1(const int* __restrict__ cnt, int* __restrict__ bsum) {
  __shared__ int sd[256];
  int t = threadIdx.x;
  int i = blockIdx.x * 256 + t;
  sd[t] = (i < NN) ? cnt[i] : 0;
  __syncthreads();
  for (int off = 128; off > 0; off >>= 1) {
    if (t < off) sd[t] += sd[t + off];
    __syncthreads();
  }
  if (t == 0) bsum[blockIdx.x] = sd[0];
}

__global__ void k_scan2(const int* __restrict__ bsum, int* __restrict__ bpre,
                        int* __restrict__ offsets, int nb) {
  __shared__ int sd[256];
  int t = threadIdx.x;
  int v = (t < nb) ? bsum[t] : 0;
  sd[t] = v;
  __syncthreads();
  for (int off = 1; off < 256; off <<= 1) {
    int x = (t >= off) ? sd[t - off] : 0;
    __syncthreads();
    sd[t] += x;
    __syncthreads();
  }
  if (t < nb) bpre[t] = sd[t] - v;
  if (t == 255) offsets[NN] = sd[255];
}

__global__ void k_scan3(const int* __restrict__ cnt, const int* __restrict__ bpre,
                        int* __restrict__ offsets, int* __restrict__ cursor) {
  __shared__ int sd[256];
  int t = threadIdx.x;
  int i = blockIdx.x * 256 + t;
  int v = (i < NN) ? cnt[i] : 0;
  sd[t] = v;
  __syncthreads();
  for (int off = 1; off < 256; off <<= 1) {
    int x = (t >= off) ? sd[t - off] : 0;
    __syncthreads();
    sd[t] += x;
    __syncthreads();
  }
  int excl = sd[t] - v + bpre[blockIdx.x];
  if (i < NN) { offsets[i] = excl; cursor[i] = excl; }
}

// scatter: srcCSR + CSR-ordered bias copy (kills eids + the biasE gather in
// the hot loop; geo has completed by stream order).
__global__ void k_scatter(const int* __restrict__ srcv,
                          const int* __restrict__ dstv,
                          const float* __restrict__ biasE,
                          int* __restrict__ cursor,
                          int* __restrict__ srcCSR,
                          float* __restrict__ biasCSR) {
  int e = blockIdx.x * 256 + threadIdx.x;
  if (e < NE) {
    int d = dstv[e];
    int pos = atomicAdd(&cursor[d], 1);
    srcCSR[pos] = srcv[e];
    float4 b4 = *(const float4*)&biasE[e * 4];
    *(float4*)&biasCSR[pos * 4] = b4;
  }
}

// ---------------------------------------------------------------------------
// FUSED per-dst attention, 4-edge-unrolled online softmax.
// (m,den,acc) is a monoid: 4 edges merge into one update (exp count 8->5,
// serial steps /4, four independent shfl chains in flight).
// ---------------------------------------------------------------------------
__global__ __launch_bounds__(128) void k_agg_fused(
    const int* __restrict__ srcCSR, const int* __restrict__ offsets,
    const float* __restrict__ biasCSR, const __bf16* __restrict__ Qb,
    const float* __restrict__ K, const __bf16* __restrict__ Vb,
    float* __restrict__ accum) {
  int b = blockIdx.x;
  int t = threadIdx.x;
  int h = t >> 5;
  int beg = offsets[b], end = offsets[b + 1];
  float kv = K[b * HID + t];

  float m = -3.0e38f, den = 0.f, acc = 0.f;
  int i = beg;
  for (; i + 3 < end; i += 4) {
    int s0 = srcCSR[i], s1 = srcCSR[i + 1], s2 = srcCSR[i + 2], s3 = srcCSR[i + 3];
    float q0 = (float)Qb[s0 * HID + t], q1 = (float)Qb[s1 * HID + t];
    float q2 = (float)Qb[s2 * HID + t], q3 = (float)Qb[s3 * HID + t];
    float v0 = (float)Vb[s0 * HID + t], v1 = (float)Vb[s1 * HID + t];
    float v2 = (float)Vb[s2 * HID + t], v3 = (float)Vb[s3 * HID + t];
    float b0 = biasCSR[i * 4 + h], b1 = biasCSR[(i + 1) * 4 + h];
    float b2 = biasCSR[(i + 2) * 4 + h], b3 = biasCSR[(i + 3) * 4 + h];
    float p0 = q0 * kv, p1 = q1 * kv, p2 = q2 * kv, p3 = q3 * kv;
#pragma unroll
    for (int off = 1; off < 32; off <<= 1) {
      p0 += __shfl_xor(p0, off, 32);
      p1 += __shfl_xor(p1, off, 32);
      p2 += __shfl_xor(p2, off, 32);
      p3 += __shfl_xor(p3, off, 32);
    }
    float sc0 = fmaf(p0, SCALE, b0), sc1 = fmaf(p1, SCALE, b1);
    float sc2 = fmaf(p2, SCALE, b2), sc3 = fmaf(p3, SCALE, b3);
    float mn = fmaxf(m, fmaxf(fmaxf(sc0, sc1), fmaxf(sc2, sc3)));
    float r = __expf(m - mn);
    float w0 = __expf(sc0 - mn), w1 = __expf(sc1 - mn);
    float w2 = __expf(sc2 - mn), w3 = __expf(sc3 - mn);
    den = fmaf(den, r, (w0 + w1) + (w2 + w3));
    acc = fmaf(acc, r, fmaf(w0, v0, fmaf(w1, v1, fmaf(w2, v2, w3 * v3))));
    m = mn;
  }
  for (; i < end; ++i) {
    int s = srcCSR[i];
    float qv = (float)Qb[s * HID + t];
    float vv = (float)Vb[s * HID + t];
    float bias = biasCSR[i * 4 + h];
    float prod = qv * kv;
#pragma unroll
    for (int off = 1; off < 32; off <<= 1) prod += __shfl_xor(prod, off, 32);
    float sc = fmaf(prod, SCALE, bias);
    float mn = fmaxf(m, sc);
    float r = __expf(m - mn);
    float w = __expf(sc - mn);
    den = fmaf(den, r, w);
    acc = fmaf(acc, r, w * vv);
    m = mn;
  }
  accum[b * HID + t] = (end > beg) ? (acc / den) : 0.f;
}

// ---------------------------------------------------------------------------
extern "C" void kernel_launch(void* const* d_in, const int* in_sizes, int n_in,
                              void* d_out, int out_size, void* d_ws, size_t ws_size,
                              hipStream_t stream) {
  const float* x = (const float*)d_in[0];
  const int* ei = (const int*)d_in[1];
  const float* rbf = (const float*)d_in[2];
  const int* isd = (const int*)d_in[3];
  const float* Wq = (const float*)d_in[4];
  const float* bq = (const float*)d_in[5];
  const float* Wk = (const float*)d_in[6];
  const float* bk = (const float*)d_in[7];
  const float* Wv = (const float*)d_in[8];
  const float* bv = (const float*)d_in[9];
  const float* Wo = (const float*)d_in[10];
  const float* bo = (const float*)d_in[11];
  const float* Wg1 = (const float*)d_in[12];
  const float* bg1 = (const float*)d_in[13];
  const float* Wg2 = (const float*)d_in[14];
  const float* bg2 = (const float*)d_in[15];
  const float* db = (const float*)d_in[16];
  const int* srcv = ei;
  const int* dstv = ei + NE;

  char* p = (char*)d_ws;
  auto alloc = [&](size_t bytes) {
    void* r = (void*)p;
    p += (bytes + 255) & ~(size_t)255;
    return r;
  };
  __bf16* Qb = (__bf16*)alloc((size_t)NN * HID * 2);
  float* Kb = (float*)alloc((size_t)NN * HID * 4);
  __bf16* Vb = (__bf16*)alloc((size_t)NN * HID * 2);
  float* biasE = (float*)alloc((size_t)NE * NH * 4);
  float* biasCSR = (float*)alloc((size_t)NE * NH * 4);
  float* accum = (float*)alloc((size_t)NN * HID * 4);
  int* cnt = (int*)alloc((size_t)NN * 4);
  int* offsets = (int*)alloc((size_t)(NN + 1) * 4);
  int* cursor = (int*)alloc((size_t)NN * 4);
  int* srcCSR = (int*)alloc((size_t)NE * 4);
  int* bsum = (int*)alloc(256 * 4);
  int* bpre = (int*)alloc(256 * 4);
  __bf16* qhi = (__bf16*)alloc(2048 * 8 * 2);
  __bf16* qlo = (__bf16*)alloc(2048 * 8 * 2);
  __bf16* khi = (__bf16*)alloc(2048 * 8 * 2);
  __bf16* klo = (__bf16*)alloc(2048 * 8 * 2);
  __bf16* vhi = (__bf16*)alloc(2048 * 8 * 2);
  __bf16* vlo = (__bf16*)alloc(2048 * 8 * 2);
  __bf16* ohi = (__bf16*)alloc(2048 * 8 * 2);
  __bf16* olo = (__bf16*)alloc(2048 * 8 * 2);
  __bf16* g1hi = (__bf16*)alloc(1024 * 8 * 2);
  __bf16* g1lo = (__bf16*)alloc(1024 * 8 * 2);

  hipMemsetAsync(cnt, 0, (size_t)NN * 4, stream);

  int gQ = (NN + 127) / 128;       // 391
  int gE = (NE + 127) / 128;       // 4688
  int gEth = (NE + 255) / 256;     // 2344
  int gS = (NN + 255) / 256;       // 196

  k_prepw_all<<<36, 256, 0, stream>>>(Wq, Wk, Wv, Wo, Wg1, qhi, qlo, khi, klo,
                                      vhi, vlo, ohi, olo, g1hi, g1lo);
  k_qkv3<<<gQ, 256, 0, stream>>>(x, qhi, qlo, khi, klo, vhi, vlo,
                                 bq, bk, bv, Qb, Kb, Vb, NN);
  k_geo_mfma<<<gE, 256, 0, stream>>>(rbf, g1hi, g1lo, bg1, Wg2, bg2,
                                     srcv, dstv, isd, db, biasE, cnt);
  k_scan1<<<gS, 256, 0, stream>>>(cnt, bsum);
  k_scan2<<<1, 256, 0, stream>>>(bsum, bpre, offsets, gS);
  k_scan3<<<gS, 256, 0, stream>>>(cnt, bpre, offsets, cursor);
  k_scatter<<<gEth, 256, 0, stream>>>(srcv, dstv, biasE, cursor, srcCSR, biasCSR);
  k_agg_fused<<<NN, 128, 0, stream>>>(srcCSR, offsets, biasCSR, Qb, Kb, Vb, accum);
  k_mm128<<<gQ, 256, 0, stream>>>(accum, ohi, olo, bo, (float*)d_out, NN);
}